// Round 6
// baseline (1999.326 us; speedup 1.0000x reference)
//
#include <hip/hip_runtime.h>
#include <hip/hip_bf16.h>

typedef __attribute__((ext_vector_type(4))) float f32x4;
typedef __attribute__((ext_vector_type(8))) short bf16x8;
typedef unsigned int   u32;
typedef unsigned short u16;

#define D_DIM 2048
#define I_DIM 768
#define NE    64
#define CAP   1024
#define NTOK  4096

__device__ __forceinline__ u32 cvt2(float a, float b) {
  __hip_bfloat162 hh = __float22bfloat162_rn(float2{a, b});
  union { __hip_bfloat162 h; u32 u; } c; c.h = hh; return c.u;
}
__device__ __forceinline__ u16 f2b(float f) {
  __hip_bfloat16 b = __float2bfloat16(f);
  union { __hip_bfloat16 b; u16 u; } c; c.b = b; return c.u;
}
// async global->LDS, 16B per lane. LDS dest = wave-uniform base + lane*16.
__device__ __forceinline__ void glp16(const void* g, void* l) {
  __builtin_amdgcn_global_load_lds(
      (const __attribute__((address_space(1))) u32*)g,
      (__attribute__((address_space(3))) u32*)l, 16, 0, 0);
}

// ---------------- x fp32 -> bf16 ----------------
__global__ __launch_bounds__(256) void k_cvt_x(const float* __restrict__ x,
                                               u16* __restrict__ xb) {
  const size_t i = ((size_t)blockIdx.x * 256 + threadIdx.x) * 8;
  float4 v0 = *(const float4*)(x + i);
  float4 v1 = *(const float4*)(x + i + 4);
  uint4 o;
  o.x = cvt2(v0.x, v0.y); o.y = cvt2(v0.z, v0.w);
  o.z = cvt2(v1.x, v1.y); o.w = cvt2(v1.z, v1.w);
  *(uint4*)(xb + i) = o;
}

// ---------------- fp32 [R][C] -> bf16 [C][R] transpose-convert, per expert ----
__global__ __launch_bounds__(256) void k_cvt_t(const float* __restrict__ in,
                                               u16* __restrict__ outp,
                                               int R, int C) {
  const int e  = blockIdx.z;
  const int c0 = blockIdx.x * 64;
  const int r0 = blockIdx.y * 64;
  const float* ip = in + (size_t)e * R * C;
  u16* op = outp + (size_t)e * R * C;

  __shared__ u16 T[64][72];
  const int t  = threadIdx.x;
  const int rr = t >> 4;         // 0..15
  const int cc = (t & 15) * 4;   // 0..60
  #pragma unroll
  for (int it = 0; it < 4; ++it) {
    const int r = rr + it * 16;
    float4 v = *(const float4*)(ip + (size_t)(r0 + r) * C + c0 + cc);
    T[cc + 0][r] = f2b(v.x);
    T[cc + 1][r] = f2b(v.y);
    T[cc + 2][r] = f2b(v.z);
    T[cc + 3][r] = f2b(v.w);
  }
  __syncthreads();
  const int cw = t >> 3;         // 0..31
  const int r8 = (t & 7) * 8;
  #pragma unroll
  for (int jt = 0; jt < 2; ++jt) {
    const int c = cw + jt * 32;
    const u16* s = &T[c][r8];
    uint4 o;
    o.x = (u32)s[0] | ((u32)s[1] << 16);
    o.y = (u32)s[2] | ((u32)s[3] << 16);
    o.z = (u32)s[4] | ((u32)s[5] << 16);
    o.w = (u32)s[6] | ((u32)s[7] << 16);
    *(uint4*)(op + (size_t)(c0 + c) * R + r0 + r8) = o;
  }
}

// ---------------- router: fp32 logits, top-8, renorm, dispatch ----------------
__global__ __launch_bounds__(256) void k_router(
    const float* __restrict__ x, const float* __restrict__ rw,
    int* __restrict__ counts, int* __restrict__ slot_token,
    float* __restrict__ slot_w)
{
  const int lane = threadIdx.x & 63;
  const int tok  = blockIdx.x * 4 + (threadIdx.x >> 6);
  const float* xr = x + (size_t)tok * D_DIM;

  float acc = 0.f;
  for (int d0 = 0; d0 < D_DIM; d0 += 64) {
    float xv = xr[d0 + lane];
    #pragma unroll
    for (int j = 0; j < 64; ++j) {
      float xj = __shfl(xv, j, 64);
      acc = fmaf(xj, rw[(size_t)(d0 + j) * NE + lane], acc);
    }
  }

  float v = acc; int vi = lane;
  float wk[8]; int ei[8];
  float mx0 = 0.f, wsum = 0.f;
  #pragma unroll
  for (int k = 0; k < 8; ++k) {
    float mv = v; int mi = vi;
    #pragma unroll
    for (int off = 32; off >= 1; off >>= 1) {
      float ov = __shfl_xor(mv, off, 64);
      int   oi = __shfl_xor(mi, off, 64);
      if (ov > mv || (ov == mv && oi < mi)) { mv = ov; mi = oi; }
    }
    if (k == 0) mx0 = mv;
    float ew = __expf(mv - mx0);
    wk[k] = ew; ei[k] = mi; wsum += ew;
    if (lane == mi) v = -3.4e38f;
  }

  if (lane == 0) {
    float inv = 1.f / wsum;
    #pragma unroll
    for (int k = 0; k < 8; ++k) {
      int ee   = ei[k];
      int slot = atomicAdd(&counts[ee], 1);
      if (slot < CAP) {
        slot_token[ee * CAP + slot] = tok;
        slot_w[ee * CAP + slot]     = wk[k] * inv;
      }
    }
  }
}

// ================= bf16-weight path, m97 geometry =================
// Single-buffered 32KB LDS, BK=64, {stage -> sync -> 32 MFMA/wave -> sync},
// 5 blocks/CU; inter-block wave overlap hides the vmcnt(0) drain.

// gate/up fused GEMM + SwiGLU -> h. grid 6144 XCD-swizzled.
// Tile 128m x (64 g + 64 u), BK=64.
__global__ __launch_bounds__(256, 5) void k_mlp1(
    const u16* __restrict__ xb, const u16* __restrict__ gT,
    const u16* __restrict__ uT, const int* __restrict__ counts,
    const int* __restrict__ slot_token, u16* __restrict__ h)
{
  const int i   = blockIdx.x;
  const int xcd = i & 7;
  const int p   = i >> 3;
  const int mt  = p & 7;
  const int pe  = p >> 3;
  const int val = pe * 8 + xcd;    // == e*12 + nt
  const int e   = val / 12;
  const int nt  = val % 12;

  int cnt = counts[e]; if (cnt > CAP) cnt = CAP;
  const int m0 = mt * 128;
  if (m0 >= cnt) return;
  const int n0 = nt * 64;

  const int t = threadIdx.x;
  const int lane = t & 63, wv = t >> 6;
  const int li = lane & 15, gq = lane >> 4;
  const int wr = wv >> 1, wc = wv & 1;

  __shared__ u16 As[8 * 128 * 8];   // [kg(8)][m(128)][8]  16 KB
  __shared__ u16 Bg[8 * 64 * 8];    //  8 KB
  __shared__ u16 Bu[8 * 64 * 8];    //  8 KB  -> 32 KB total

  // A staging: wave wv -> m-half (wv&1), kg = (wv>>1) + 2q
  const int mhA  = wv & 1;
  const int kgA0 = wv >> 1;
  const int tok  = slot_token[e * CAP + m0 + mhA * 64 + lane];  // dead slots -> 0
  const u16* xrow = xb + (size_t)tok * D_DIM;

  // B staging: waves 0-1 stage gate, 2-3 stage up; kg = (wv&1) + 2q, n = lane
  const u16* wTb = ((wv >> 1) ? uT : gT) + (size_t)e * D_DIM * I_DIM
                   + (size_t)(n0 + lane) * D_DIM;
  u16* Bbase = (wv >> 1) ? Bu : Bg;
  const int kgB0 = wv & 1;

  f32x4 ag[4][2], au[4][2];
  #pragma unroll
  for (int m = 0; m < 4; ++m)
    #pragma unroll
    for (int n = 0; n < 2; ++n) {
      f32x4 z = {0.f, 0.f, 0.f, 0.f};
      ag[m][n] = z; au[m][n] = z;
    }

  for (int kk = 0; kk < D_DIM; kk += 64) {
    // ---- stage K-tile (8 glp16 per wave, zero VALU) ----
    #pragma unroll
    for (int q = 0; q < 4; ++q) {
      const int kga = kgA0 + 2 * q;
      glp16(xrow + kk + kga * 8, &As[(kga * 128 + mhA * 64) * 8]);
      const int kgb = kgB0 + 2 * q;
      glp16(wTb + kk + kgb * 8, Bbase + (kgb * 64) * 8);
    }
    __syncthreads();   // drains glps (vmcnt0); tile visible

    // ---- compute: 2 kc x 16 MFMA ----
    #pragma unroll
    for (int kc = 0; kc < 2; ++kc) {
      const int kg = kc * 4 + gq;
      bf16x8 a0 = *(const bf16x8*)&As[(kg * 128 + wr * 64 +      li) * 8];
      bf16x8 a1 = *(const bf16x8*)&As[(kg * 128 + wr * 64 + 16 + li) * 8];
      bf16x8 a2 = *(const bf16x8*)&As[(kg * 128 + wr * 64 + 32 + li) * 8];
      bf16x8 a3 = *(const bf16x8*)&As[(kg * 128 + wr * 64 + 48 + li) * 8];
      bf16x8 g0 = *(const bf16x8*)&Bg[(kg * 64 + wc * 32 +      li) * 8];
      bf16x8 g1 = *(const bf16x8*)&Bg[(kg * 64 + wc * 32 + 16 + li) * 8];
      bf16x8 u0 = *(const bf16x8*)&Bu[(kg * 64 + wc * 32 +      li) * 8];
      bf16x8 u1 = *(const bf16x8*)&Bu[(kg * 64 + wc * 32 + 16 + li) * 8];
      ag[0][0] = __builtin_amdgcn_mfma_f32_16x16x32_bf16(a0, g0, ag[0][0], 0, 0, 0);
      ag[1][0] = __builtin_amdgcn_mfma_f32_16x16x32_bf16(a1, g0, ag[1][0], 0, 0, 0);
      ag[2][0] = __builtin_amdgcn_mfma_f32_16x16x32_bf16(a2, g0, ag[2][0], 0, 0, 0);
      ag[3][0] = __builtin_amdgcn_mfma_f32_16x16x32_bf16(a3, g0, ag[3][0], 0, 0, 0);
      ag[0][1] = __builtin_amdgcn_mfma_f32_16x16x32_bf16(a0, g1, ag[0][1], 0, 0, 0);
      ag[1][1] = __builtin_amdgcn_mfma_f32_16x16x32_bf16(a1, g1, ag[1][1], 0, 0, 0);
      ag[2][1] = __builtin_amdgcn_mfma_f32_16x16x32_bf16(a2, g1, ag[2][1], 0, 0, 0);
      ag[3][1] = __builtin_amdgcn_mfma_f32_16x16x32_bf16(a3, g1, ag[3][1], 0, 0, 0);
      au[0][0] = __builtin_amdgcn_mfma_f32_16x16x32_bf16(a0, u0, au[0][0], 0, 0, 0);
      au[1][0] = __builtin_amdgcn_mfma_f32_16x16x32_bf16(a1, u0, au[1][0], 0, 0, 0);
      au[2][0] = __builtin_amdgcn_mfma_f32_16x16x32_bf16(a2, u0, au[2][0], 0, 0, 0);
      au[3][0] = __builtin_amdgcn_mfma_f32_16x16x32_bf16(a3, u0, au[3][0], 0, 0, 0);
      au[0][1] = __builtin_amdgcn_mfma_f32_16x16x32_bf16(a0, u1, au[0][1], 0, 0, 0);
      au[1][1] = __builtin_amdgcn_mfma_f32_16x16x32_bf16(a1, u1, au[1][1], 0, 0, 0);
      au[2][1] = __builtin_amdgcn_mfma_f32_16x16x32_bf16(a2, u1, au[2][1], 0, 0, 0);
      au[3][1] = __builtin_amdgcn_mfma_f32_16x16x32_bf16(a3, u1, au[3][1], 0, 0, 0);
    }
    __syncthreads();   // reads done before next stage overwrites
  }

  #pragma unroll
  for (int mf = 0; mf < 4; ++mf) {
    #pragma unroll
    for (int j = 0; j < 4; ++j) {
      const int slot = m0 + wr * 64 + mf * 16 + gq * 4 + j;
      u16* hr = h + (size_t)(e * CAP + slot) * I_DIM + n0 + wc * 32 + li;
      #pragma unroll
      for (int nf = 0; nf < 2; ++nf) {
        float gg = ag[mf][nf][j];
        float uu = au[mf][nf][j];
        hr[nf * 16] = f2b(gg * uu / (1.f + __expf(-gg)));
      }
    }
  }
}

// down GEMM + weighted scatter-add. grid 8192 XCD-swizzled.
// Tile 128m x 128n, BK=64.
__global__ __launch_bounds__(256, 5) void k_mlp2(
    const u16* __restrict__ h, const u16* __restrict__ dT,
    const int* __restrict__ counts, const int* __restrict__ slot_token,
    const float* __restrict__ slot_w, float* __restrict__ out)
{
  const int i   = blockIdx.x;
  const int xcd = i & 7;
  const int p   = i >> 3;
  const int mt  = p & 7;
  const int pe  = p >> 3;
  const int val = pe * 8 + xcd;    // == e*16 + nt
  const int e   = val >> 4;
  const int nt  = val & 15;

  int cnt = counts[e]; if (cnt > CAP) cnt = CAP;
  const int m0 = mt * 128;
  if (m0 >= cnt) return;
  const int n0 = nt * 128;

  const int t = threadIdx.x;
  const int lane = t & 63, wv = t >> 6;
  const int li = lane & 15, gq = lane >> 4;
  const int wm = (wv >> 1) * 64, wn = (wv & 1) * 64;

  __shared__ u16 As[8 * 128 * 8];   // [kg(8)][m(128)][8]  16 KB
  __shared__ u16 Bt[8 * 128 * 8];   // [kg(8)][n(128)][8]  16 KB -> 32 KB

  const int mh   = wv & 1;
  const int kgA0 = wv >> 1;
  const u16* hrow = h + (size_t)(e * CAP + m0 + mh * 64 + lane) * I_DIM;

  const int nh   = wv & 1;
  const int kgB0 = wv >> 1;
  const u16* drow = dT + (size_t)e * I_DIM * D_DIM
                    + (size_t)(n0 + nh * 64 + lane) * I_DIM;

  f32x4 acc[4][4];
  #pragma unroll
  for (int m = 0; m < 4; ++m)
    #pragma unroll
    for (int n = 0; n < 4; ++n) { f32x4 z = {0.f,0.f,0.f,0.f}; acc[m][n] = z; }

  for (int kk = 0; kk < I_DIM; kk += 64) {
    #pragma unroll
    for (int q = 0; q < 4; ++q) {
      const int kga = kgA0 + 2 * q;
      glp16(hrow + kk + kga * 8, &As[(kga * 128 + mh * 64) * 8]);
      const int kgb = kgB0 + 2 * q;
      glp16(drow + kk + kgb * 8, &Bt[(kgb * 128 + nh * 64) * 8]);
    }
    __syncthreads();

    #pragma unroll
    for (int kc = 0; kc < 2; ++kc) {
      const int kg = kc * 4 + gq;
      bf16x8 a[4], b[4];
      #pragma unroll
      for (int mf = 0; mf < 4; ++mf)
        a[mf] = *(const bf16x8*)&As[(kg * 128 + wm + mf * 16 + li) * 8];
      #pragma unroll
      for (int nf = 0; nf < 4; ++nf)
        b[nf] = *(const bf16x8*)&Bt[(kg * 128 + wn + nf * 16 + li) * 8];
      #pragma unroll
      for (int mf = 0; mf < 4; ++mf)
        #pragma unroll
        for (int nf = 0; nf < 4; ++nf)
          acc[mf][nf] = __builtin_amdgcn_mfma_f32_16x16x32_bf16(a[mf], b[nf], acc[mf][nf], 0, 0, 0);
    }
    __syncthreads();
  }

  #pragma unroll
  for (int mf = 0; mf < 4; ++mf) {
    #pragma unroll
    for (int j = 0; j < 4; ++j) {
      const int slot = m0 + wm + mf * 16 + gq * 4 + j;
      if (slot < cnt) {
        const int   tk  = slot_token[e * CAP + slot];
        const float wgt = slot_w[e * CAP + slot];
        float* orow = out + (size_t)tk * D_DIM + n0 + wn + li;
        #pragma unroll
        for (int nf = 0; nf < 4; ++nf)
          atomicAdd(&orow[nf * 16], wgt * acc[mf][nf][j]);
      }
    }
  }
}

// ================= fallback path (fp32 weights, round-4 structure) =================

__global__ __launch_bounds__(256, 4) void k_mlp1f(
    const u16* __restrict__ xb, const float* __restrict__ gate,
    const float* __restrict__ up, const int* __restrict__ counts,
    const int* __restrict__ slot_token, u16* __restrict__ h)
{
  const int i   = blockIdx.x;
  const int xcd = i & 7;
  const int p   = i >> 3;
  const int mt  = p & 7;
  const int pe  = p >> 3;
  const int val = pe * 8 + xcd;
  const int e   = val / 12;
  const int nt  = val % 12;

  int cnt = counts[e]; if (cnt > CAP) cnt = CAP;
  const int m0 = mt * 128;
  if (m0 >= cnt) return;
  const int n0 = nt * 64;

  const int t = threadIdx.x;
  const int lane = t & 63, wv = t >> 6;
  const int li = lane & 15, gq = lane >> 4;
  const int wr = wv >> 1, wc = wv & 1;

  __shared__ u16 As[2][4 * 128 * 8];
  __shared__ u16 Bg[2][4 * 64 * 8];
  __shared__ u16 Bu[2][4 * 64 * 8];

  const int mh  = wv & 1;
  const int kgA = (wv >> 1) * 2;
  const int tok = slot_token[e * CAP + m0 + mh * 64 + lane];
  const u16* xrow = xb + (size_t)tok * D_DIM;

  const float* gb = gate + (size_t)e * D_DIM * I_DIM + n0 + lane;
  const float* ub = up   + (size_t)e * D_DIM * I_DIM + n0 + lane;

  f32x4 ag[4][2], au[4][2];
  #pragma unroll
  for (int m = 0; m < 4; ++m)
    #pragma unroll
    for (int n = 0; n < 2; ++n) {
      f32x4 z = {0.f, 0.f, 0.f, 0.f};
      ag[m][n] = z; au[m][n] = z;
    }

  float gv[8], uv[8];
  glp16(xrow + kgA * 8,       &As[0][(kgA * 128 + mh * 64) * 8]);
  glp16(xrow + (kgA + 1) * 8, &As[0][((kgA + 1) * 128 + mh * 64) * 8]);
  #pragma unroll
  for (int j = 0; j < 8; ++j) {
    gv[j] = gb[(size_t)(wv * 8 + j) * I_DIM];
    uv[j] = ub[(size_t)(wv * 8 + j) * I_DIM];
  }
  {
    uint4 og, ou;
    og.x = cvt2(gv[0], gv[1]); og.y = cvt2(gv[2], gv[3]);
    og.z = cvt2(gv[4], gv[5]); og.w = cvt2(gv[6], gv[7]);
    ou.x = cvt2(uv[0], uv[1]); ou.y = cvt2(uv[2], uv[3]);
    ou.z = cvt2(uv[4], uv[5]); ou.w = cvt2(uv[6], uv[7]);
    *(uint4*)&Bg[0][(wv * 64 + lane) * 8] = og;
    *(uint4*)&Bu[0][(wv * 64 + lane) * 8] = ou;
  }
  __syncthreads();

  int buf = 0;
  for (int kk = 0; kk < D_DIM; kk += 32) {
    const bool more = (kk + 32) < D_DIM;
    if (more) {
      glp16(xrow + kk + 32 + kgA * 8,       &As[buf ^ 1][(kgA * 128 + mh * 64) * 8]);
      glp16(xrow + kk + 32 + (kgA + 1) * 8, &As[buf ^ 1][((kgA + 1) * 128 + mh * 64) * 8]);
      #pragma unroll
      for (int j = 0; j < 8; ++j) {
        gv[j] = gb[(size_t)(kk + 32 + wv * 8 + j) * I_DIM];
        uv[j] = ub[(size_t)(kk + 32 + wv * 8 + j) * I_DIM];
      }
    }
    {
      bf16x8 a0 = *(const bf16x8*)&As[buf][(gq * 128 + wr * 64 +      li) * 8];
      bf16x8 a1 = *(const bf16x8*)&As[buf][(gq * 128 + wr * 64 + 16 + li) * 8];
      bf16x8 a2 = *(const bf16x8*)&As[buf][(gq * 128 + wr * 64 + 32 + li) * 8];
      bf16x8 a3 = *(const bf16x8*)&As[buf][(gq * 128 + wr * 64 + 48 + li) * 8];
      bf16x8 g0 = *(const bf16x8*)&Bg[buf][(gq * 64 + wc * 32 +      li) * 8];
      bf16x8 g1 = *(const bf16x8*)&Bg[buf][(gq * 64 + wc * 32 + 16 + li) * 8];
      bf16x8 u0 = *(const bf16x8*)&Bu[buf][(gq * 64 + wc * 32 +      li) * 8];
      bf16x8 u1 = *(const bf16x8*)&Bu[buf][(gq * 64 + wc * 32 + 16 + li) * 8];
      ag[0][0] = __builtin_amdgcn_mfma_f32_16x16x32_bf16(a0, g0, ag[0][0], 0, 0, 0);
      ag[1][0] = __builtin_amdgcn_mfma_f32_16x16x32_bf16(a1, g0, ag[1][0], 0, 0, 0);
      ag[2][0] = __builtin_amdgcn_mfma_f32_16x16x32_bf16(a2, g0, ag[2][0], 0, 0, 0);
      ag[3][0] = __builtin_amdgcn_mfma_f32_16x16x32_bf16(a3, g0, ag[3][0], 0, 0, 0);
      ag[0][1] = __builtin_amdgcn_mfma_f32_16x16x32_bf16(a0, g1, ag[0][1], 0, 0, 0);
      ag[1][1] = __builtin_amdgcn_mfma_f32_16x16x32_bf16(a1, g1, ag[1][1], 0, 0, 0);
      ag[2][1] = __builtin_amdgcn_mfma_f32_16x16x32_bf16(a2, g1, ag[2][1], 0, 0, 0);
      ag[3][1] = __builtin_amdgcn_mfma_f32_16x16x32_bf16(a3, g1, ag[3][1], 0, 0, 0);
      au[0][0] = __builtin_amdgcn_mfma_f32_16x16x32_bf16(a0, u0, au[0][0], 0, 0, 0);
      au[1][0] = __builtin_amdgcn_mfma_f32_16x16x32_bf16(a1, u0, au[1][0], 0, 0, 0);
      au[2][0] = __builtin_amdgcn_mfma_f32_16x16x32_bf16(a2, u0, au[2][0], 0, 0, 0);
      au[3][0] = __builtin_amdgcn_mfma_f32_16x16x32_bf16(a3, u0, au[3][0], 0, 0, 0);
      au[0][1] = __builtin_amdgcn_mfma_f32_16x16x32_bf16(a0, u1, au[0][1], 0, 0, 0);
      au[1][1] = __builtin_amdgcn_mfma_f32_16x16x32_bf16(a1, u1, au[1][1], 0, 0, 0);
      au[2][1] = __builtin_amdgcn_mfma_f32_16x16x32_bf16(a2, u1, au[2][1], 0, 0, 0);
      au[3][1] = __builtin_amdgcn_mfma_f32_16x16x32_bf16(a3, u1, au[3][1], 0, 0, 0);
    }
    if (more) {
      uint4 og, ou;
      og.x = cvt2(gv[0], gv[1]); og.y = cvt2(gv[2], gv[3]);
      og.z = cvt2(gv[4], gv[5]); og.w = cvt2(gv[6], gv[7]);
      ou.x = cvt2(uv[0], uv[1]); ou.y = cvt2(uv[2], uv[3]);
      ou.z = cvt2(uv[4], uv[5]); ou.w = cvt2(uv[6], uv[7]);
      *(uint4*)&Bg[buf ^ 1][(wv * 64 + lane) * 8] = og;
      *(uint4*)&Bu[buf ^ 1][(wv * 64 + lane) * 8] = ou;
    }
    __syncthreads();
    buf ^= 1;
  }

  #pragma unroll
  for (int mf = 0; mf < 4; ++mf) {
    #pragma unroll
    for (int j = 0; j < 4; ++j) {
      const int slot = m0 + wr * 64 + mf * 16 + gq * 4 + j;
      u16* hr = h + (size_t)(e * CAP + slot) * I_DIM + n0 + wc * 32 + li;
      #pragma unroll
      for (int nf = 0; nf < 2; ++nf) {
        float gg = ag[mf][nf][j];
        float uu = au[mf][nf][j];
        hr[nf * 16] = f2b(gg * uu / (1.f + __expf(-gg)));
      }
    }
  }
}

__global__ __launch_bounds__(256, 4) void k_mlp2f(
    const u16* __restrict__ h, const float* __restrict__ down,
    const int* __restrict__ counts, const int* __restrict__ slot_token,
    const float* __restrict__ slot_w, float* __restrict__ out)
{
  const int i   = blockIdx.x;
  const int xcd = i & 7;
  const int p   = i >> 3;
  const int mt  = p & 7;
  const int pe  = p >> 3;
  const int val = pe * 8 + xcd;
  const int e   = val >> 4;
  const int nt  = val & 15;

  int cnt = counts[e]; if (cnt > CAP) cnt = CAP;
  const int m0 = mt * 128;
  if (m0 >= cnt) return;
  const int n0 = nt * 128;

  const int t = threadIdx.x;
  const int lane = t & 63, wv = t >> 6;
  const int li = lane & 15, gq = lane >> 4;
  const int wm = (wv >> 1) * 64, wn = (wv & 1) * 64;

  __shared__ u16 As[2][4 * 128 * 8];
  __shared__ u16 Bt[2][4 * 128 * 8];

  const int mh  = wv & 1;
  const int kgA = (wv >> 1) * 2;
  const u16* hrow = h + (size_t)(e * CAP + m0 + mh * 64 + lane) * I_DIM;

  const int nB  = t & 127;
  const int kgB = (t >> 7) * 2;
  const float* db = down + (size_t)e * I_DIM * D_DIM + n0 + nB;

  f32x4 acc[4][4];
  #pragma unroll
  for (int m = 0; m < 4; ++m)
    #pragma unroll
    for (int n = 0; n < 4; ++n) { f32x4 z = {0.f,0.f,0.f,0.f}; acc[m][n] = z; }

  float dv[2][8];
  glp16(hrow + kgA * 8,       &As[0][(kgA * 128 + mh * 64) * 8]);
  glp16(hrow + (kgA + 1) * 8, &As[0][((kgA + 1) * 128 + mh * 64) * 8]);
  #pragma unroll
  for (int c = 0; c < 2; ++c)
    #pragma unroll
    for (int j = 0; j < 8; ++j)
      dv[c][j] = db[(size_t)((kgB + c) * 8 + j) * D_DIM];
  #pragma unroll
  for (int c = 0; c < 2; ++c) {
    uint4 o;
    o.x = cvt2(dv[c][0], dv[c][1]); o.y = cvt2(dv[c][2], dv[c][3]);
    o.z = cvt2(dv[c][4], dv[c][5]); o.w = cvt2(dv[c][6], dv[c][7]);
    *(uint4*)&Bt[0][((kgB + c) * 128 + nB) * 8] = o;
  }
  __syncthreads();

  int buf = 0;
  for (int kk = 0; kk < I_DIM; kk += 32) {
    const bool more = (kk + 32) < I_DIM;
    if (more) {
      glp16(hrow + kk + 32 + kgA * 8,       &As[buf ^ 1][(kgA * 128 + mh * 64) * 8]);
      glp16(hrow + kk + 32 + (kgA + 1) * 8, &As[buf ^ 1][((kgA + 1) * 128 + mh * 64) * 8]);
      #pragma unroll
      for (int c = 0; c < 2; ++c)
        #pragma unroll
        for (int j = 0; j < 8; ++j)
          dv[c][j] = db[(size_t)(kk + 32 + (kgB + c) * 8 + j) * D_DIM];
    }
    {
      bf16x8 a[4], b[4];
      #pragma unroll
      for (int mf = 0; mf < 4; ++mf)
        a[mf] = *(const bf16x8*)&As[buf][(gq * 128 + wm + mf * 16 + li) * 8];
      #pragma unroll
      for (int nf = 0; nf < 4; ++nf)
        b[nf] = *(const bf16x8*)&Bt[buf][(gq * 128 + wn + nf * 16 + li) * 8];
      #pragma unroll
      for (int mf = 0; mf < 4; ++mf)
        #pragma unroll
        for (int nf = 0; nf < 4; ++nf)
          acc[mf][nf] = __builtin_amdgcn_mfma_f32_16x16x32_bf16(a[mf], b[nf], acc[mf][nf], 0, 0, 0);
    }
    if (more) {
      #pragma unroll
      for (int c = 0; c < 2; ++c) {
        uint4 o;
        o.x = cvt2(dv[c][0], dv[c][1]); o.y = cvt2(dv[c][2], dv[c][3]);
        o.z = cvt2(dv[c][4], dv[c][5]); o.w = cvt2(dv[c][6], dv[c][7]);
        *(uint4*)&Bt[buf ^ 1][((kgB + c) * 128 + nB) * 8] = o;
      }
    }
    __syncthreads();
    buf ^= 1;
  }

  #pragma unroll
  for (int mf = 0; mf < 4; ++mf) {
    #pragma unroll
    for (int j = 0; j < 4; ++j) {
      const int slot = m0 + wm + mf * 16 + gq * 4 + j;
      if (slot < cnt) {
        const int   tk  = slot_token[e * CAP + slot];
        const float wgt = slot_w[e * CAP + slot];
        float* orow = out + (size_t)tk * D_DIM + n0 + wn + li;
        #pragma unroll
        for (int nf = 0; nf < 4; ++nf)
          atomicAdd(&orow[nf * 16], wgt * acc[mf][nf][j]);
      }
    }
  }
}

extern "C" void kernel_launch(void* const* d_in, const int* in_sizes, int n_in,
                              void* d_out, int out_size, void* d_ws, size_t ws_size,
                              hipStream_t stream) {
  const float* x    = (const float*)d_in[0];
  const float* rw   = (const float*)d_in[1];
  const float* gate = (const float*)d_in[2];
  const float* up   = (const float*)d_in[3];
  const float* down = (const float*)d_in[4];
  float* out = (float*)d_out;

  char* ws = (char*)d_ws;
  int*   counts     = (int*)ws;                        // 1 KB pad
  int*   slot_token = (int*)(ws + 1024);               // 256 KB
  float* slot_w     = (float*)(ws + 1024 + 262144);    // 256 KB
  u16*   xb         = (u16*)(ws + 1024 + 524288);      // 16.78 MB
  u16*   h          = (u16*)(ws + 1024 + 524288 + 16777216);  // 100.7 MB
  const size_t base = 1024 + 524288 + 16777216 + 100663296ull;
  const size_t WSLAB = 201326592ull;                   // one bf16 weight slab
  u16* gT = (u16*)(ws + base);
  u16* uT = (u16*)(ws + base + WSLAB);
  u16* dT = (u16*)(ws + base + 2 * WSLAB);
  const bool wb = ws_size >= base + 3 * WSLAB;         // 722 MB needed

  hipMemsetAsync(counts, 0, NE * sizeof(int), stream);
  hipMemsetAsync(slot_token, 0, (size_t)NE * CAP * sizeof(int), stream);
  hipMemsetAsync(out, 0, (size_t)out_size * sizeof(float), stream);

  k_cvt_x <<<dim3((NTOK * D_DIM) / (256 * 8)), 256, 0, stream>>>(x, xb);
  k_router<<<dim3(NTOK / 4),                   256, 0, stream>>>(x, rw, counts, slot_token, slot_w);

  if (wb) {
    k_cvt_t<<<dim3(12, 32, NE), 256, 0, stream>>>(gate, gT, D_DIM, I_DIM);
    k_cvt_t<<<dim3(12, 32, NE), 256, 0, stream>>>(up,   uT, D_DIM, I_DIM);
    k_cvt_t<<<dim3(32, 12, NE), 256, 0, stream>>>(down, dT, I_DIM, D_DIM);
    k_mlp1<<<dim3(6144), 256, 0, stream>>>(xb, gT, uT, counts, slot_token, h);
    k_mlp2<<<dim3(8192), 256, 0, stream>>>(h, dT, counts, slot_token, slot_w, out);
  } else {
    k_mlp1f<<<dim3(6144), 256, 0, stream>>>(xb, gate, up, counts, slot_token, h);
    k_mlp2f<<<dim3(8192), 256, 0, stream>>>(h, down, counts, slot_token, slot_w, out);
  }
}

// Round 7
// 1756.653 us; speedup vs baseline: 1.1381x; 1.1381x over previous
//
#include <hip/hip_runtime.h>
#include <hip/hip_bf16.h>

typedef __attribute__((ext_vector_type(4))) float f32x4;
typedef __attribute__((ext_vector_type(8))) short bf16x8;
typedef unsigned int   u32;
typedef unsigned short u16;

#define D_DIM 2048
#define I_DIM 768
#define NE    64
#define CAP   1024
#define NTOK  4096

__device__ __forceinline__ u32 cvt2(float a, float b) {
  __hip_bfloat162 hh = __float22bfloat162_rn(float2{a, b});
  union { __hip_bfloat162 h; u32 u; } c; c.h = hh; return c.u;
}
__device__ __forceinline__ u16 f2b(float f) {
  __hip_bfloat16 b = __float2bfloat16(f);
  union { __hip_bfloat16 b; u16 u; } c; c.b = b; return c.u;
}
// async global->LDS, 16B per lane. LDS dest = wave-uniform base + lane*16.
__device__ __forceinline__ void glp16(const void* g, void* l) {
  __builtin_amdgcn_global_load_lds(
      (const __attribute__((address_space(1))) u32*)g,
      (__attribute__((address_space(3))) u32*)l, 16, 0, 0);
}

// counted vmcnt wait (T4) + raw barrier with compiler memory fences
#define VMW(n) asm volatile("s_waitcnt vmcnt(" #n ")" ::: "memory")
#define BARF   do { __builtin_amdgcn_s_barrier(); \
                    asm volatile("" ::: "memory"); } while (0)

// ---------------- x fp32 -> bf16 ----------------
__global__ __launch_bounds__(256) void k_cvt_x(const float* __restrict__ x,
                                               u16* __restrict__ xb) {
  const size_t i = ((size_t)blockIdx.x * 256 + threadIdx.x) * 8;
  float4 v0 = *(const float4*)(x + i);
  float4 v1 = *(const float4*)(x + i + 4);
  uint4 o;
  o.x = cvt2(v0.x, v0.y); o.y = cvt2(v0.z, v0.w);
  o.z = cvt2(v1.x, v1.y); o.w = cvt2(v1.z, v1.w);
  *(uint4*)(xb + i) = o;
}

// ---------------- fp32 [R][C] -> bf16 [C][R] transpose-convert, per expert ----
__global__ __launch_bounds__(256) void k_cvt_t(const float* __restrict__ in,
                                               u16* __restrict__ outp,
                                               int R, int C) {
  const int e  = blockIdx.z;
  const int c0 = blockIdx.x * 64;
  const int r0 = blockIdx.y * 64;
  const float* ip = in + (size_t)e * R * C;
  u16* op = outp + (size_t)e * R * C;

  __shared__ u16 T[64][72];
  const int t  = threadIdx.x;
  const int rr = t >> 4;
  const int cc = (t & 15) * 4;
  #pragma unroll
  for (int it = 0; it < 4; ++it) {
    const int r = rr + it * 16;
    float4 v = *(const float4*)(ip + (size_t)(r0 + r) * C + c0 + cc);
    T[cc + 0][r] = f2b(v.x);
    T[cc + 1][r] = f2b(v.y);
    T[cc + 2][r] = f2b(v.z);
    T[cc + 3][r] = f2b(v.w);
  }
  __syncthreads();
  const int cw = t >> 3;
  const int r8 = (t & 7) * 8;
  #pragma unroll
  for (int jt = 0; jt < 2; ++jt) {
    const int c = cw + jt * 32;
    const u16* s = &T[c][r8];
    uint4 o;
    o.x = (u32)s[0] | ((u32)s[1] << 16);
    o.y = (u32)s[2] | ((u32)s[3] << 16);
    o.z = (u32)s[4] | ((u32)s[5] << 16);
    o.w = (u32)s[6] | ((u32)s[7] << 16);
    *(uint4*)(op + (size_t)(c0 + c) * R + r0 + r8) = o;
  }
}

// ---------------- router: fp32 logits, top-8, renorm, dispatch ----------------
__global__ __launch_bounds__(256) void k_router(
    const float* __restrict__ x, const float* __restrict__ rw,
    int* __restrict__ counts, int* __restrict__ slot_token,
    float* __restrict__ slot_w)
{
  const int lane = threadIdx.x & 63;
  const int tok  = blockIdx.x * 4 + (threadIdx.x >> 6);
  const float* xr = x + (size_t)tok * D_DIM;

  float acc = 0.f;
  for (int d0 = 0; d0 < D_DIM; d0 += 64) {
    float xv = xr[d0 + lane];
    #pragma unroll
    for (int j = 0; j < 64; ++j) {
      float xj = __shfl(xv, j, 64);
      acc = fmaf(xj, rw[(size_t)(d0 + j) * NE + lane], acc);
    }
  }

  float v = acc; int vi = lane;
  float wk[8]; int ei[8];
  float mx0 = 0.f, wsum = 0.f;
  #pragma unroll
  for (int k = 0; k < 8; ++k) {
    float mv = v; int mi = vi;
    #pragma unroll
    for (int off = 32; off >= 1; off >>= 1) {
      float ov = __shfl_xor(mv, off, 64);
      int   oi = __shfl_xor(mi, off, 64);
      if (ov > mv || (ov == mv && oi < mi)) { mv = ov; mi = oi; }
    }
    if (k == 0) mx0 = mv;
    float ew = __expf(mv - mx0);
    wk[k] = ew; ei[k] = mi; wsum += ew;
    if (lane == mi) v = -3.4e38f;
  }

  if (lane == 0) {
    float inv = 1.f / wsum;
    #pragma unroll
    for (int k = 0; k < 8; ++k) {
      int ee   = ei[k];
      int slot = atomicAdd(&counts[ee], 1);
      if (slot < CAP) {
        slot_token[ee * CAP + slot] = tok;
        slot_w[ee * CAP + slot]     = wk[k] * inv;
      }
    }
  }
}

// ================= bf16-weight path: depth-3 counted-vmcnt pipeline =================
// 4 LDS buffers x BK=32; per iter: vmcnt(8) -> s_barrier -> issue glp(j+3) -> MFMA(j).
// Stage-j loads fly ~3 iterations before use; vmcnt never drains to 0 in the loop.

// gate/up fused GEMM + SwiGLU -> h. grid 6144 XCD-swizzled. Tile 128m x (64g+64u).
__global__ __launch_bounds__(256, 2) void k_mlp1(
    const u16* __restrict__ xb, const u16* __restrict__ gT,
    const u16* __restrict__ uT, const int* __restrict__ counts,
    const int* __restrict__ slot_token, u16* __restrict__ h)
{
  const int i   = blockIdx.x;
  const int xcd = i & 7;
  const int p   = i >> 3;
  const int mt  = p & 7;
  const int pe  = p >> 3;
  const int val = pe * 8 + xcd;    // == e*12 + nt
  const int e   = val / 12;
  const int nt  = val % 12;

  int cnt = counts[e]; if (cnt > CAP) cnt = CAP;
  const int m0 = mt * 128;
  if (m0 >= cnt) return;
  const int n0 = nt * 64;

  const int t = threadIdx.x;
  const int lane = t & 63, wv = t >> 6;
  const int li = lane & 15, gq = lane >> 4;
  const int wr = wv >> 1, wc = wv & 1;

  __shared__ u16 As[4][4 * 128 * 8];   // [buf][kg(4)][m(128)][8]  32 KB
  __shared__ u16 Bg[4][4 * 64 * 8];    // 16 KB
  __shared__ u16 Bu[4][4 * 64 * 8];    // 16 KB -> 64 KB total

  // staging: wave wv owns kg=wv for A(mh=0), A(mh=1), Bg, Bu -> 4 glp/iter
  const int tok0 = slot_token[e * CAP + m0 + lane];        // dead slots -> 0
  const int tok1 = slot_token[e * CAP + m0 + 64 + lane];
  const u16* xr0 = xb + (size_t)tok0 * D_DIM;
  const u16* xr1 = xb + (size_t)tok1 * D_DIM;
  const u16* gb  = gT + (size_t)e * D_DIM * I_DIM + (size_t)(n0 + lane) * D_DIM;
  const u16* ub  = uT + (size_t)e * D_DIM * I_DIM + (size_t)(n0 + lane) * D_DIM;

  f32x4 ag[4][2], au[4][2];
  #pragma unroll
  for (int m = 0; m < 4; ++m)
    #pragma unroll
    for (int n = 0; n < 2; ++n) {
      f32x4 z = {0.f, 0.f, 0.f, 0.f};
      ag[m][n] = z; au[m][n] = z;
    }

#define M1_ISSUE(JS, SB)                                           \
  {                                                                \
    const int kks = (JS) * 32;                                     \
    glp16(xr0 + kks + wv * 8, &As[SB][(wv * 128) * 8]);            \
    glp16(xr1 + kks + wv * 8, &As[SB][(wv * 128 + 64) * 8]);       \
    glp16(gb  + kks + wv * 8, &Bg[SB][(wv * 64) * 8]);             \
    glp16(ub  + kks + wv * 8, &Bu[SB][(wv * 64) * 8]);             \
  }

#define M1_MFMA(BB)                                                              \
  {                                                                              \
    bf16x8 a0 = *(const bf16x8*)&As[BB][(gq * 128 + wr * 64 +      li) * 8];     \
    bf16x8 a1 = *(const bf16x8*)&As[BB][(gq * 128 + wr * 64 + 16 + li) * 8];     \
    bf16x8 a2 = *(const bf16x8*)&As[BB][(gq * 128 + wr * 64 + 32 + li) * 8];     \
    bf16x8 a3 = *(const bf16x8*)&As[BB][(gq * 128 + wr * 64 + 48 + li) * 8];     \
    bf16x8 g0 = *(const bf16x8*)&Bg[BB][(gq * 64 + wc * 32 +      li) * 8];      \
    bf16x8 g1 = *(const bf16x8*)&Bg[BB][(gq * 64 + wc * 32 + 16 + li) * 8];      \
    bf16x8 u0 = *(const bf16x8*)&Bu[BB][(gq * 64 + wc * 32 +      li) * 8];      \
    bf16x8 u1 = *(const bf16x8*)&Bu[BB][(gq * 64 + wc * 32 + 16 + li) * 8];      \
    ag[0][0] = __builtin_amdgcn_mfma_f32_16x16x32_bf16(a0, g0, ag[0][0], 0, 0, 0); \
    ag[1][0] = __builtin_amdgcn_mfma_f32_16x16x32_bf16(a1, g0, ag[1][0], 0, 0, 0); \
    ag[2][0] = __builtin_amdgcn_mfma_f32_16x16x32_bf16(a2, g0, ag[2][0], 0, 0, 0); \
    ag[3][0] = __builtin_amdgcn_mfma_f32_16x16x32_bf16(a3, g0, ag[3][0], 0, 0, 0); \
    ag[0][1] = __builtin_amdgcn_mfma_f32_16x16x32_bf16(a0, g1, ag[0][1], 0, 0, 0); \
    ag[1][1] = __builtin_amdgcn_mfma_f32_16x16x32_bf16(a1, g1, ag[1][1], 0, 0, 0); \
    ag[2][1] = __builtin_amdgcn_mfma_f32_16x16x32_bf16(a2, g1, ag[2][1], 0, 0, 0); \
    ag[3][1] = __builtin_amdgcn_mfma_f32_16x16x32_bf16(a3, g1, ag[3][1], 0, 0, 0); \
    au[0][0] = __builtin_amdgcn_mfma_f32_16x16x32_bf16(a0, u0, au[0][0], 0, 0, 0); \
    au[1][0] = __builtin_amdgcn_mfma_f32_16x16x32_bf16(a1, u0, au[1][0], 0, 0, 0); \
    au[2][0] = __builtin_amdgcn_mfma_f32_16x16x32_bf16(a2, u0, au[2][0], 0, 0, 0); \
    au[3][0] = __builtin_amdgcn_mfma_f32_16x16x32_bf16(a3, u0, au[3][0], 0, 0, 0); \
    au[0][1] = __builtin_amdgcn_mfma_f32_16x16x32_bf16(a0, u1, au[0][1], 0, 0, 0); \
    au[1][1] = __builtin_amdgcn_mfma_f32_16x16x32_bf16(a1, u1, au[1][1], 0, 0, 0); \
    au[2][1] = __builtin_amdgcn_mfma_f32_16x16x32_bf16(a2, u1, au[2][1], 0, 0, 0); \
    au[3][1] = __builtin_amdgcn_mfma_f32_16x16x32_bf16(a3, u1, au[3][1], 0, 0, 0); \
  }

  // prologue: stages 0,1,2 in flight (12 glp/wave)
  M1_ISSUE(0, 0); M1_ISSUE(1, 1); M1_ISSUE(2, 2);

  for (int jc = 0; jc < 15; ++jc) {            // j = 4jc .. 4jc+3 (0..59)
    const int j = jc * 4;
    VMW(8); BARF; M1_ISSUE(j + 3, 3); M1_MFMA(0);
    VMW(8); BARF; M1_ISSUE(j + 4, 0); M1_MFMA(1);
    VMW(8); BARF; M1_ISSUE(j + 5, 1); M1_MFMA(2);
    VMW(8); BARF; M1_ISSUE(j + 6, 2); M1_MFMA(3);
  }
  // tail j = 60..63
  VMW(8); BARF; M1_ISSUE(63, 3); M1_MFMA(0);
  VMW(8); BARF;                  M1_MFMA(1);
  VMW(4); BARF;                  M1_MFMA(2);
  VMW(0); BARF;                  M1_MFMA(3);

#undef M1_ISSUE
#undef M1_MFMA

  // epilogue: h = silu(g) * u, bf16
  #pragma unroll
  for (int mf = 0; mf < 4; ++mf) {
    #pragma unroll
    for (int j = 0; j < 4; ++j) {
      const int slot = m0 + wr * 64 + mf * 16 + gq * 4 + j;
      u16* hr = h + (size_t)(e * CAP + slot) * I_DIM + n0 + wc * 32 + li;
      #pragma unroll
      for (int nf = 0; nf < 2; ++nf) {
        float gg = ag[mf][nf][j];
        float uu = au[mf][nf][j];
        hr[nf * 16] = f2b(gg * uu / (1.f + __expf(-gg)));
      }
    }
  }
}

// down GEMM + weighted scatter-add. grid 8192 XCD-swizzled. Tile 128m x 128n.
__global__ __launch_bounds__(256, 2) void k_mlp2(
    const u16* __restrict__ h, const u16* __restrict__ dT,
    const int* __restrict__ counts, const int* __restrict__ slot_token,
    const float* __restrict__ slot_w, float* __restrict__ out)
{
  const int i   = blockIdx.x;
  const int xcd = i & 7;
  const int p   = i >> 3;
  const int mt  = p & 7;
  const int pe  = p >> 3;
  const int val = pe * 8 + xcd;    // == e*16 + nt
  const int e   = val >> 4;
  const int nt  = val & 15;

  int cnt = counts[e]; if (cnt > CAP) cnt = CAP;
  const int m0 = mt * 128;
  if (m0 >= cnt) return;
  const int n0 = nt * 128;

  const int t = threadIdx.x;
  const int lane = t & 63, wv = t >> 6;
  const int li = lane & 15, gq = lane >> 4;
  const int wm = (wv >> 1) * 64, wn = (wv & 1) * 64;

  __shared__ u16 As[4][4 * 128 * 8];   // 32 KB
  __shared__ u16 Bt[4][4 * 128 * 8];   // 32 KB -> 64 KB

  const u16* hr0 = h + (size_t)(e * CAP + m0 + lane) * I_DIM;
  const u16* hr1 = h + (size_t)(e * CAP + m0 + 64 + lane) * I_DIM;
  const u16* dr0 = dT + (size_t)e * I_DIM * D_DIM + (size_t)(n0 + lane) * I_DIM;
  const u16* dr1 = dT + (size_t)e * I_DIM * D_DIM + (size_t)(n0 + 64 + lane) * I_DIM;

  f32x4 acc[4][4];
  #pragma unroll
  for (int m = 0; m < 4; ++m)
    #pragma unroll
    for (int n = 0; n < 4; ++n) { f32x4 z = {0.f,0.f,0.f,0.f}; acc[m][n] = z; }

#define M2_ISSUE(JS, SB)                                           \
  {                                                                \
    const int kks = (JS) * 32;                                     \
    glp16(hr0 + kks + wv * 8, &As[SB][(wv * 128) * 8]);            \
    glp16(hr1 + kks + wv * 8, &As[SB][(wv * 128 + 64) * 8]);       \
    glp16(dr0 + kks + wv * 8, &Bt[SB][(wv * 128) * 8]);            \
    glp16(dr1 + kks + wv * 8, &Bt[SB][(wv * 128 + 64) * 8]);       \
  }

#define M2_MFMA(BB)                                                                \
  {                                                                                \
    bf16x8 a0 = *(const bf16x8*)&As[BB][(gq * 128 + wm +      li) * 8];            \
    bf16x8 a1 = *(const bf16x8*)&As[BB][(gq * 128 + wm + 16 + li) * 8];            \
    bf16x8 a2 = *(const bf16x8*)&As[BB][(gq * 128 + wm + 32 + li) * 8];            \
    bf16x8 a3 = *(const bf16x8*)&As[BB][(gq * 128 + wm + 48 + li) * 8];            \
    bf16x8 b0 = *(const bf16x8*)&Bt[BB][(gq * 128 + wn +      li) * 8];            \
    bf16x8 b1 = *(const bf16x8*)&Bt[BB][(gq * 128 + wn + 16 + li) * 8];            \
    bf16x8 b2 = *(const bf16x8*)&Bt[BB][(gq * 128 + wn + 32 + li) * 8];            \
    bf16x8 b3 = *(const bf16x8*)&Bt[BB][(gq * 128 + wn + 48 + li) * 8];            \
    acc[0][0] = __builtin_amdgcn_mfma_f32_16x16x32_bf16(a0, b0, acc[0][0], 0, 0, 0); \
    acc[0][1] = __builtin_amdgcn_mfma_f32_16x16x32_bf16(a0, b1, acc[0][1], 0, 0, 0); \
    acc[0][2] = __builtin_amdgcn_mfma_f32_16x16x32_bf16(a0, b2, acc[0][2], 0, 0, 0); \
    acc[0][3] = __builtin_amdgcn_mfma_f32_16x16x32_bf16(a0, b3, acc[0][3], 0, 0, 0); \
    acc[1][0] = __builtin_amdgcn_mfma_f32_16x16x32_bf16(a1, b0, acc[1][0], 0, 0, 0); \
    acc[1][1] = __builtin_amdgcn_mfma_f32_16x16x32_bf16(a1, b1, acc[1][1], 0, 0, 0); \
    acc[1][2] = __builtin_amdgcn_mfma_f32_16x16x32_bf16(a1, b2, acc[1][2], 0, 0, 0); \
    acc[1][3] = __builtin_amdgcn_mfma_f32_16x16x32_bf16(a1, b3, acc[1][3], 0, 0, 0); \
    acc[2][0] = __builtin_amdgcn_mfma_f32_16x16x32_bf16(a2, b0, acc[2][0], 0, 0, 0); \
    acc[2][1] = __builtin_amdgcn_mfma_f32_16x16x32_bf16(a2, b1, acc[2][1], 0, 0, 0); \
    acc[2][2] = __builtin_amdgcn_mfma_f32_16x16x32_bf16(a2, b2, acc[2][2], 0, 0, 0); \
    acc[2][3] = __builtin_amdgcn_mfma_f32_16x16x32_bf16(a2, b3, acc[2][3], 0, 0, 0); \
    acc[3][0] = __builtin_amdgcn_mfma_f32_16x16x32_bf16(a3, b0, acc[3][0], 0, 0, 0); \
    acc[3][1] = __builtin_amdgcn_mfma_f32_16x16x32_bf16(a3, b1, acc[3][1], 0, 0, 0); \
    acc[3][2] = __builtin_amdgcn_mfma_f32_16x16x32_bf16(a3, b2, acc[3][2], 0, 0, 0); \
    acc[3][3] = __builtin_amdgcn_mfma_f32_16x16x32_bf16(a3, b3, acc[3][3], 0, 0, 0); \
  }

  M2_ISSUE(0, 0); M2_ISSUE(1, 1); M2_ISSUE(2, 2);

  for (int jc = 0; jc < 5; ++jc) {             // j = 0..19
    const int j = jc * 4;
    VMW(8); BARF; M2_ISSUE(j + 3, 3); M2_MFMA(0);
    VMW(8); BARF; M2_ISSUE(j + 4, 0); M2_MFMA(1);
    VMW(8); BARF; M2_ISSUE(j + 5, 1); M2_MFMA(2);
    VMW(8); BARF; M2_ISSUE(j + 6, 2); M2_MFMA(3);
  }
  // tail j = 20..23
  VMW(8); BARF; M2_ISSUE(23, 3); M2_MFMA(0);
  VMW(8); BARF;                  M2_MFMA(1);
  VMW(4); BARF;                  M2_MFMA(2);
  VMW(0); BARF;                  M2_MFMA(3);

#undef M2_ISSUE
#undef M2_MFMA

  #pragma unroll
  for (int mf = 0; mf < 4; ++mf) {
    #pragma unroll
    for (int j = 0; j < 4; ++j) {
      const int slot = m0 + wm + mf * 16 + gq * 4 + j;
      if (slot < cnt) {
        const int   tk  = slot_token[e * CAP + slot];
        const float wgt = slot_w[e * CAP + slot];
        float* orow = out + (size_t)tk * D_DIM + n0 + wn + li;
        #pragma unroll
        for (int nf = 0; nf < 4; ++nf)
          atomicAdd(&orow[nf * 16], wgt * acc[mf][nf][j]);
      }
    }
  }
}

// ================= fallback path (fp32 weights, round-4 structure) =================

__global__ __launch_bounds__(256, 4) void k_mlp1f(
    const u16* __restrict__ xb, const float* __restrict__ gate,
    const float* __restrict__ up, const int* __restrict__ counts,
    const int* __restrict__ slot_token, u16* __restrict__ h)
{
  const int i   = blockIdx.x;
  const int xcd = i & 7;
  const int p   = i >> 3;
  const int mt  = p & 7;
  const int pe  = p >> 3;
  const int val = pe * 8 + xcd;
  const int e   = val / 12;
  const int nt  = val % 12;

  int cnt = counts[e]; if (cnt > CAP) cnt = CAP;
  const int m0 = mt * 128;
  if (m0 >= cnt) return;
  const int n0 = nt * 64;

  const int t = threadIdx.x;
  const int lane = t & 63, wv = t >> 6;
  const int li = lane & 15, gq = lane >> 4;
  const int wr = wv >> 1, wc = wv & 1;

  __shared__ u16 As[2][4 * 128 * 8];
  __shared__ u16 Bg[2][4 * 64 * 8];
  __shared__ u16 Bu[2][4 * 64 * 8];

  const int mh  = wv & 1;
  const int kgA = (wv >> 1) * 2;
  const int tok = slot_token[e * CAP + m0 + mh * 64 + lane];
  const u16* xrow = xb + (size_t)tok * D_DIM;

  const float* gb = gate + (size_t)e * D_DIM * I_DIM + n0 + lane;
  const float* ub = up   + (size_t)e * D_DIM * I_DIM + n0 + lane;

  f32x4 ag[4][2], au[4][2];
  #pragma unroll
  for (int m = 0; m < 4; ++m)
    #pragma unroll
    for (int n = 0; n < 2; ++n) {
      f32x4 z = {0.f, 0.f, 0.f, 0.f};
      ag[m][n] = z; au[m][n] = z;
    }

  float gv[8], uv[8];
  glp16(xrow + kgA * 8,       &As[0][(kgA * 128 + mh * 64) * 8]);
  glp16(xrow + (kgA + 1) * 8, &As[0][((kgA + 1) * 128 + mh * 64) * 8]);
  #pragma unroll
  for (int j = 0; j < 8; ++j) {
    gv[j] = gb[(size_t)(wv * 8 + j) * I_DIM];
    uv[j] = ub[(size_t)(wv * 8 + j) * I_DIM];
  }
  {
    uint4 og, ou;
    og.x = cvt2(gv[0], gv[1]); og.y = cvt2(gv[2], gv[3]);
    og.z = cvt2(gv[4], gv[5]); og.w = cvt2(gv[6], gv[7]);
    ou.x = cvt2(uv[0], uv[1]); ou.y = cvt2(uv[2], uv[3]);
    ou.z = cvt2(uv[4], uv[5]); ou.w = cvt2(uv[6], uv[7]);
    *(uint4*)&Bg[0][(wv * 64 + lane) * 8] = og;
    *(uint4*)&Bu[0][(wv * 64 + lane) * 8] = ou;
  }
  __syncthreads();

  int buf = 0;
  for (int kk = 0; kk < D_DIM; kk += 32) {
    const bool more = (kk + 32) < D_DIM;
    if (more) {
      glp16(xrow + kk + 32 + kgA * 8,       &As[buf ^ 1][(kgA * 128 + mh * 64) * 8]);
      glp16(xrow + kk + 32 + (kgA + 1) * 8, &As[buf ^ 1][((kgA + 1) * 128 + mh * 64) * 8]);
      #pragma unroll
      for (int j = 0; j < 8; ++j) {
        gv[j] = gb[(size_t)(kk + 32 + wv * 8 + j) * I_DIM];
        uv[j] = ub[(size_t)(kk + 32 + wv * 8 + j) * I_DIM];
      }
    }
    {
      bf16x8 a0 = *(const bf16x8*)&As[buf][(gq * 128 + wr * 64 +      li) * 8];
      bf16x8 a1 = *(const bf16x8*)&As[buf][(gq * 128 + wr * 64 + 16 + li) * 8];
      bf16x8 a2 = *(const bf16x8*)&As[buf][(gq * 128 + wr * 64 + 32 + li) * 8];
      bf16x8 a3 = *(const bf16x8*)&As[buf][(gq * 128 + wr * 64 + 48 + li) * 8];
      bf16x8 g0 = *(const bf16x8*)&Bg[buf][(gq * 64 + wc * 32 +      li) * 8];
      bf16x8 g1 = *(const bf16x8*)&Bg[buf][(gq * 64 + wc * 32 + 16 + li) * 8];
      bf16x8 u0 = *(const bf16x8*)&Bu[buf][(gq * 64 + wc * 32 +      li) * 8];
      bf16x8 u1 = *(const bf16x8*)&Bu[buf][(gq * 64 + wc * 32 + 16 + li) * 8];
      ag[0][0] = __builtin_amdgcn_mfma_f32_16x16x32_bf16(a0, g0, ag[0][0], 0, 0, 0);
      ag[1][0] = __builtin_amdgcn_mfma_f32_16x16x32_bf16(a1, g0, ag[1][0], 0, 0, 0);
      ag[2][0] = __builtin_amdgcn_mfma_f32_16x16x32_bf16(a2, g0, ag[2][0], 0, 0, 0);
      ag[3][0] = __builtin_amdgcn_mfma_f32_16x16x32_bf16(a3, g0, ag[3][0], 0, 0, 0);
      ag[0][1] = __builtin_amdgcn_mfma_f32_16x16x32_bf16(a0, g1, ag[0][1], 0, 0, 0);
      ag[1][1] = __builtin_amdgcn_mfma_f32_16x16x32_bf16(a1, g1, ag[1][1], 0, 0, 0);
      ag[2][1] = __builtin_amdgcn_mfma_f32_16x16x32_bf16(a2, g1, ag[2][1], 0, 0, 0);
      ag[3][1] = __builtin_amdgcn_mfma_f32_16x16x32_bf16(a3, g1, ag[3][1], 0, 0, 0);
      au[0][0] = __builtin_amdgcn_mfma_f32_16x16x32_bf16(a0, u0, au[0][0], 0, 0, 0);
      au[1][0] = __builtin_amdgcn_mfma_f32_16x16x32_bf16(a1, u0, au[1][0], 0, 0, 0);
      au[2][0] = __builtin_amdgcn_mfma_f32_16x16x32_bf16(a2, u0, au[2][0], 0, 0, 0);
      au[3][0] = __builtin_amdgcn_mfma_f32_16x16x32_bf16(a3, u0, au[3][0], 0, 0, 0);
      au[0][1] = __builtin_amdgcn_mfma_f32_16x16x32_bf16(a0, u1, au[0][1], 0, 0, 0);
      au[1][1] = __builtin_amdgcn_mfma_f32_16x16x32_bf16(a1, u1, au[1][1], 0, 0, 0);
      au[2][1] = __builtin_amdgcn_mfma_f32_16x16x32_bf16(a2, u1, au[2][1], 0, 0, 0);
      au[3][1] = __builtin_amdgcn_mfma_f32_16x16x32_bf16(a3, u1, au[3][1], 0, 0, 0);
    }
    if (more) {
      uint4 og, ou;
      og.x = cvt2(gv[0], gv[1]); og.y = cvt2(gv[2], gv[3]);
      og.z = cvt2(gv[4], gv[5]); og.w = cvt2(gv[6], gv[7]);
      ou.x = cvt2(uv[0], uv[1]); ou.y = cvt2(uv[2], uv[3]);
      ou.z = cvt2(uv[4], uv[5]); ou.w = cvt2(uv[6], uv[7]);
      *(uint4*)&Bg[buf ^ 1][(wv * 64 + lane) * 8] = og;
      *(uint4*)&Bu[buf ^ 1][(wv * 64 + lane) * 8] = ou;
    }
    __syncthreads();
    buf ^= 1;
  }

  #pragma unroll
  for (int mf = 0; mf < 4; ++mf) {
    #pragma unroll
    for (int j = 0; j < 4; ++j) {
      const int slot = m0 + wr * 64 + mf * 16 + gq * 4 + j;
      u16* hr = h + (size_t)(e * CAP + slot) * I_DIM + n0 + wc * 32 + li;
      #pragma unroll
      for (int nf = 0; nf < 2; ++nf) {
        float gg = ag[mf][nf][j];
        float uu = au[mf][nf][j];
        hr[nf * 16] = f2b(gg * uu / (1.f + __expf(-gg)));
      }
    }
  }
}

__global__ __launch_bounds__(256, 4) void k_mlp2f(
    const u16* __restrict__ h, const float* __restrict__ down,
    const int* __restrict__ counts, const int* __restrict__ slot_token,
    const float* __restrict__ slot_w, float* __restrict__ out)
{
  const int i   = blockIdx.x;
  const int xcd = i & 7;
  const int p   = i >> 3;
  const int mt  = p & 7;
  const int pe  = p >> 3;
  const int val = pe * 8 + xcd;
  const int e   = val >> 4;
  const int nt  = val & 15;

  int cnt = counts[e]; if (cnt > CAP) cnt = CAP;
  const int m0 = mt * 128;
  if (m0 >= cnt) return;
  const int n0 = nt * 128;

  const int t = threadIdx.x;
  const int lane = t & 63, wv = t >> 6;
  const int li = lane & 15, gq = lane >> 4;
  const int wm = (wv >> 1) * 64, wn = (wv & 1) * 64;

  __shared__ u16 As[2][4 * 128 * 8];
  __shared__ u16 Bt[2][4 * 128 * 8];

  const int mh  = wv & 1;
  const int kgA = (wv >> 1) * 2;
  const u16* hrow = h + (size_t)(e * CAP + m0 + mh * 64 + lane) * I_DIM;

  const int nB  = t & 127;
  const int kgB = (t >> 7) * 2;
  const float* db = down + (size_t)e * I_DIM * D_DIM + n0 + nB;

  f32x4 acc[4][4];
  #pragma unroll
  for (int m = 0; m < 4; ++m)
    #pragma unroll
    for (int n = 0; n < 4; ++n) { f32x4 z = {0.f,0.f,0.f,0.f}; acc[m][n] = z; }

  float dv[2][8];
  glp16(hrow + kgA * 8,       &As[0][(kgA * 128 + mh * 64) * 8]);
  glp16(hrow + (kgA + 1) * 8, &As[0][((kgA + 1) * 128 + mh * 64) * 8]);
  #pragma unroll
  for (int c = 0; c < 2; ++c)
    #pragma unroll
    for (int j = 0; j < 8; ++j)
      dv[c][j] = db[(size_t)((kgB + c) * 8 + j) * D_DIM];
  #pragma unroll
  for (int c = 0; c < 2; ++c) {
    uint4 o;
    o.x = cvt2(dv[c][0], dv[c][1]); o.y = cvt2(dv[c][2], dv[c][3]);
    o.z = cvt2(dv[c][4], dv[c][5]); o.w = cvt2(dv[c][6], dv[c][7]);
    *(uint4*)&Bt[0][((kgB + c) * 128 + nB) * 8] = o;
  }
  __syncthreads();

  int buf = 0;
  for (int kk = 0; kk < I_DIM; kk += 32) {
    const bool more = (kk + 32) < I_DIM;
    if (more) {
      glp16(hrow + kk + 32 + kgA * 8,       &As[buf ^ 1][(kgA * 128 + mh * 64) * 8]);
      glp16(hrow + kk + 32 + (kgA + 1) * 8, &As[buf ^ 1][((kgA + 1) * 128 + mh * 64) * 8]);
      #pragma unroll
      for (int c = 0; c < 2; ++c)
        #pragma unroll
        for (int j = 0; j < 8; ++j)
          dv[c][j] = db[(size_t)(kk + 32 + (kgB + c) * 8 + j) * D_DIM];
    }
    {
      bf16x8 a[4], b[4];
      #pragma unroll
      for (int mf = 0; mf < 4; ++mf)
        a[mf] = *(const bf16x8*)&As[buf][(gq * 128 + wm + mf * 16 + li) * 8];
      #pragma unroll
      for (int nf = 0; nf < 4; ++nf)
        b[nf] = *(const bf16x8*)&Bt[buf][(gq * 128 + wn + nf * 16 + li) * 8];
      #pragma unroll
      for (int mf = 0; mf < 4; ++mf)
        #pragma unroll
        for (int nf = 0; nf < 4; ++nf)
          acc[mf][nf] = __builtin_amdgcn_mfma_f32_16x16x32_bf16(a[mf], b[nf], acc[mf][nf], 0, 0, 0);
    }
    if (more) {
      #pragma unroll
      for (int c = 0; c < 2; ++c) {
        uint4 o;
        o.x = cvt2(dv[c][0], dv[c][1]); o.y = cvt2(dv[c][2], dv[c][3]);
        o.z = cvt2(dv[c][4], dv[c][5]); o.w = cvt2(dv[c][6], dv[c][7]);
        *(uint4*)&Bt[buf ^ 1][((kgB + c) * 128 + nB) * 8] = o;
      }
    }
    __syncthreads();
    buf ^= 1;
  }

  #pragma unroll
  for (int mf = 0; mf < 4; ++mf) {
    #pragma unroll
    for (int j = 0; j < 4; ++j) {
      const int slot = m0 + wm + mf * 16 + gq * 4 + j;
      if (slot < cnt) {
        const int   tk  = slot_token[e * CAP + slot];
        const float wgt = slot_w[e * CAP + slot];
        float* orow = out + (size_t)tk * D_DIM + n0 + wn + li;
        #pragma unroll
        for (int nf = 0; nf < 4; ++nf)
          atomicAdd(&orow[nf * 16], wgt * acc[mf][nf][j]);
      }
    }
  }
}

extern "C" void kernel_launch(void* const* d_in, const int* in_sizes, int n_in,
                              void* d_out, int out_size, void* d_ws, size_t ws_size,
                              hipStream_t stream) {
  const float* x    = (const float*)d_in[0];
  const float* rw   = (const float*)d_in[1];
  const float* gate = (const float*)d_in[2];
  const float* up   = (const float*)d_in[3];
  const float* down = (const float*)d_in[4];
  float* out = (float*)d_out;

  char* ws = (char*)d_ws;
  int*   counts     = (int*)ws;                        // 1 KB pad
  int*   slot_token = (int*)(ws + 1024);               // 256 KB
  float* slot_w     = (float*)(ws + 1024 + 262144);    // 256 KB
  u16*   xb         = (u16*)(ws + 1024 + 524288);      // 16.78 MB
  u16*   h          = (u16*)(ws + 1024 + 524288 + 16777216);  // 100.7 MB
  const size_t base = 1024 + 524288 + 16777216 + 100663296ull;
  const size_t WSLAB = 201326592ull;                   // one bf16 weight slab
  u16* gT = (u16*)(ws + base);
  u16* uT = (u16*)(ws + base + WSLAB);
  u16* dT = (u16*)(ws + base + 2 * WSLAB);
  const bool wb = ws_size >= base + 3 * WSLAB;         // 722 MB needed

  hipMemsetAsync(counts, 0, NE * sizeof(int), stream);
  hipMemsetAsync(slot_token, 0, (size_t)NE * CAP * sizeof(int), stream);
  hipMemsetAsync(out, 0, (size_t)out_size * sizeof(float), stream);

  k_cvt_x <<<dim3((NTOK * D_DIM) / (256 * 8)), 256, 0, stream>>>(x, xb);
  k_router<<<dim3(NTOK / 4),                   256, 0, stream>>>(x, rw, counts, slot_token, slot_w);

  if (wb) {
    k_cvt_t<<<dim3(12, 32, NE), 256, 0, stream>>>(gate, gT, D_DIM, I_DIM);
    k_cvt_t<<<dim3(12, 32, NE), 256, 0, stream>>>(up,   uT, D_DIM, I_DIM);
    k_cvt_t<<<dim3(32, 12, NE), 256, 0, stream>>>(down, dT, I_DIM, D_DIM);
    k_mlp1<<<dim3(6144), 256, 0, stream>>>(xb, gT, uT, counts, slot_token, h);
    k_mlp2<<<dim3(8192), 256, 0, stream>>>(h, dT, counts, slot_token, slot_w, out);
  } else {
    k_mlp1f<<<dim3(6144), 256, 0, stream>>>(xb, gate, up, counts, slot_token, h);
    k_mlp2f<<<dim3(8192), 256, 0, stream>>>(h, down, counts, slot_token, slot_w, out);
  }
}

// Round 8
// 1632.688 us; speedup vs baseline: 1.2246x; 1.0759x over previous
//
#include <hip/hip_runtime.h>
#include <hip/hip_bf16.h>

typedef __attribute__((ext_vector_type(4))) float f32x4;
typedef __attribute__((ext_vector_type(8))) short bf16x8;
typedef __attribute__((ext_vector_type(8))) unsigned short us8;
typedef unsigned int   u32;
typedef unsigned short u16;

#define D_DIM 2048
#define I_DIM 768
#define NE    64
#define CAP   1024
#define NTOK  4096

__device__ __forceinline__ u32 cvt2(float a, float b) {
  __hip_bfloat162 hh = __float22bfloat162_rn(float2{a, b});
  union { __hip_bfloat162 h; u32 u; } c; c.h = hh; return c.u;
}
__device__ __forceinline__ u16 f2b(float f) {
  __hip_bfloat16 b = __float2bfloat16(f);
  union { __hip_bfloat16 b; u16 u; } c; c.b = b; return c.u;
}
// async global->LDS, 16B per lane. LDS dest = wave-uniform base + lane*16.
__device__ __forceinline__ void glp16(const void* g, void* l) {
  __builtin_amdgcn_global_load_lds(
      (const __attribute__((address_space(1))) u32*)g,
      (__attribute__((address_space(3))) u32*)l, 16, 0, 0);
}

#define VMW(n) asm volatile("s_waitcnt vmcnt(" #n ")" ::: "memory")
#define BARF   do { __builtin_amdgcn_s_barrier(); \
                    asm volatile("" ::: "memory"); } while (0)

// ---------------- x fp32 -> bf16 ----------------
__global__ __launch_bounds__(256) void k_cvt_x(const float* __restrict__ x,
                                               u16* __restrict__ xb) {
  const size_t i = ((size_t)blockIdx.x * 256 + threadIdx.x) * 8;
  float4 v0 = *(const float4*)(x + i);
  float4 v1 = *(const float4*)(x + i + 4);
  uint4 o;
  o.x = cvt2(v0.x, v0.y); o.y = cvt2(v0.z, v0.w);
  o.z = cvt2(v1.x, v1.y); o.w = cvt2(v1.z, v1.w);
  *(uint4*)(xb + i) = o;
}

// ---------------- router: fp32 logits, top-8, renorm, dispatch ----------------
__global__ __launch_bounds__(256) void k_router(
    const float* __restrict__ x, const float* __restrict__ rw,
    int* __restrict__ counts, int* __restrict__ slot_token,
    float* __restrict__ slot_w)
{
  const int lane = threadIdx.x & 63;
  const int tok  = blockIdx.x * 4 + (threadIdx.x >> 6);
  const float* xr = x + (size_t)tok * D_DIM;

  float acc = 0.f;
  for (int d0 = 0; d0 < D_DIM; d0 += 64) {
    float xv = xr[d0 + lane];
    #pragma unroll
    for (int j = 0; j < 64; ++j) {
      float xj = __shfl(xv, j, 64);
      acc = fmaf(xj, rw[(size_t)(d0 + j) * NE + lane], acc);
    }
  }

  float v = acc; int vi = lane;
  float wk[8]; int ei[8];
  float mx0 = 0.f, wsum = 0.f;
  #pragma unroll
  for (int k = 0; k < 8; ++k) {
    float mv = v; int mi = vi;
    #pragma unroll
    for (int off = 32; off >= 1; off >>= 1) {
      float ov = __shfl_xor(mv, off, 64);
      int   oi = __shfl_xor(mi, off, 64);
      if (ov > mv || (ov == mv && oi < mi)) { mv = ov; mi = oi; }
    }
    if (k == 0) mx0 = mv;
    float ew = __expf(mv - mx0);
    wk[k] = ew; ei[k] = mi; wsum += ew;
    if (lane == mi) v = -3.4e38f;
  }

  if (lane == 0) {
    float inv = 1.f / wsum;
    #pragma unroll
    for (int k = 0; k < 8; ++k) {
      int ee   = ei[k];
      int slot = atomicAdd(&counts[ee], 1);
      if (slot < CAP) {
        slot_token[ee * CAP + slot] = tok;
        slot_w[ee * CAP + slot]     = wk[k] * inv;
      }
    }
  }
}

// ---------------- weight pack: fp32 [R][C] -> bf16 [C/64][R/8][64][8] per e ----
// grid (C/64, R/64, E). Coalesced reads, LDS transpose, 8KB contiguous writes.
__global__ __launch_bounds__(256) void k_wpack(const float* __restrict__ in,
                                               u16* __restrict__ outp,
                                               int R, int C) {
  const int e  = blockIdx.z;
  const int c0 = blockIdx.x * 64;
  const int r0 = blockIdx.y * 64;
  const float* ip = in + (size_t)e * R * C;
  // out tile base: [e][c0/64][r0/8][64][8]
  u16* op = outp + (size_t)e * (size_t)(C / 64) * (R / 8) * 512
                 + ((size_t)(c0 / 64) * (R / 8) + (r0 / 8)) * 512;

  __shared__ u16 T[64][76];     // T[n][k]
  const int t  = threadIdx.x;
  const int rr = t >> 4;        // 0..15 (k)
  const int cc = (t & 15) * 4;  // 0..60 (n)
  #pragma unroll
  for (int it = 0; it < 4; ++it) {
    const int r = rr + it * 16;
    float4 v = *(const float4*)(ip + (size_t)(r0 + r) * C + c0 + cc);
    T[cc + 0][r] = f2b(v.x);
    T[cc + 1][r] = f2b(v.y);
    T[cc + 2][r] = f2b(v.z);
    T[cc + 3][r] = f2b(v.w);
  }
  __syncthreads();
  const int n = t & 63;
  #pragma unroll
  for (int p = 0; p < 2; ++p) {
    const int c = (t >> 6) + p * 4;           // kcell 0..7
    const u16* s = &T[n][c * 8];
    uint4 o;
    o.x = (u32)s[0] | ((u32)s[1] << 16);
    o.y = (u32)s[2] | ((u32)s[3] << 16);
    o.z = (u32)s[4] | ((u32)s[5] << 16);
    o.w = (u32)s[6] | ((u32)s[7] << 16);
    *(uint4*)(op + ((size_t)c * 64 + n) * 8) = o;
  }
}

// ---------------- x pack: gather tokens -> xeT[e][kcell(256)][1024][8] --------
// grid (D/256=8, CAP/64=16, E). Dead slots zeroed.
__global__ __launch_bounds__(256) void k_xpack(
    const u16* __restrict__ xb, const int* __restrict__ counts,
    const int* __restrict__ slot_token, u16* __restrict__ xeT)
{
  const int e   = blockIdx.z;
  const int s0  = blockIdx.y * 64;
  const int kc0 = blockIdx.x * 32;       // cell index base; k0 = kc0*8
  int cnt = counts[e]; if (cnt > CAP) cnt = CAP;

  __shared__ u16 T[64][264];             // T[slot][k-local], 16B-aligned pitch
  const int t = threadIdx.x;
  const int r = t >> 2;                  // slot-local 0..63
  const int q = t & 3;
  const int  tok  = slot_token[e * CAP + s0 + r];
  const bool live = (s0 + r) < cnt;
  const u16* src = xb + (size_t)tok * D_DIM + kc0 * 8;

  #pragma unroll
  for (int it = 0; it < 8; ++it) {
    const int kl = it * 32 + q * 8;
    us8 v = {0, 0, 0, 0, 0, 0, 0, 0};
    if (live) v = *(const us8*)(src + kl);
    *(us8*)&T[r][kl] = v;
  }
  __syncthreads();

  u16* dst = xeT + (size_t)e * 2097152 + (size_t)kc0 * 8192 + (size_t)s0 * 8;
  const int sl = t & 63;
  #pragma unroll
  for (int p = 0; p < 8; ++p) {
    const int c = (t >> 6) + p * 4;      // cell-local 0..31
    const u16* s = &T[sl][c * 8];
    uint4 o = *(const uint4*)s;
    *(uint4*)(dst + (size_t)c * 8192 + sl * 8) = o;
  }
}

// ================= packed path GEMMs: depth-3 counted-vmcnt, coalesced glp ====

// gate/up fused GEMM + SwiGLU -> h_pack. grid 6144 XCD-swizzled.
__global__ __launch_bounds__(256, 2) void k_mlp1p(
    const u16* __restrict__ xeT, const u16* __restrict__ Gpk,
    const u16* __restrict__ Upk, const int* __restrict__ counts,
    u16* __restrict__ hP)
{
  const int i   = blockIdx.x;
  const int xcd = i & 7;
  const int p   = i >> 3;
  const int mt  = p & 7;
  const int pe  = p >> 3;
  const int val = pe * 8 + xcd;    // == e*12 + nt
  const int e   = val / 12;
  const int nt  = val % 12;

  int cnt = counts[e]; if (cnt > CAP) cnt = CAP;
  const int m0 = mt * 128;
  if (m0 >= cnt) return;
  const int n0 = nt * 64;

  const int t = threadIdx.x;
  const int lane = t & 63, wv = t >> 6;
  const int li = lane & 15, gq = lane >> 4;
  const int wr = wv >> 1, wc = wv & 1;

  __shared__ u16 As[4][4 * 128 * 8];   // 32 KB
  __shared__ u16 Bg[4][4 * 64 * 8];    // 16 KB
  __shared__ u16 Bu[4][4 * 64 * 8];    // 16 KB

  const u16* xeA = xeT + (size_t)e * 2097152;                    // 256*8192
  const u16* gbp = Gpk + (size_t)e * 1572864 + (size_t)nt * 131072;
  const u16* ubp = Upk + (size_t)e * 1572864 + (size_t)nt * 131072;

  f32x4 ag[4][2], au[4][2];
  #pragma unroll
  for (int m = 0; m < 4; ++m)
    #pragma unroll
    for (int n = 0; n < 2; ++n) {
      f32x4 z = {0.f, 0.f, 0.f, 0.f};
      ag[m][n] = z; au[m][n] = z;
    }

#define M1_ISSUE(JS, SB)                                                    \
  {                                                                         \
    const size_t cell = (size_t)(JS) * 4 + wv;                              \
    glp16(xeA + cell * 8192 + (m0 + lane) * 8,      &As[SB][(wv * 128) * 8]);      \
    glp16(xeA + cell * 8192 + (m0 + 64 + lane) * 8, &As[SB][(wv * 128 + 64) * 8]); \
    glp16(gbp + cell * 512 + lane * 8, &Bg[SB][(wv * 64) * 8]);             \
    glp16(ubp + cell * 512 + lane * 8, &Bu[SB][(wv * 64) * 8]);             \
  }

#define M1_MFMA(BB)                                                              \
  {                                                                              \
    bf16x8 a0 = *(const bf16x8*)&As[BB][(gq * 128 + wr * 64 +      li) * 8];     \
    bf16x8 a1 = *(const bf16x8*)&As[BB][(gq * 128 + wr * 64 + 16 + li) * 8];     \
    bf16x8 a2 = *(const bf16x8*)&As[BB][(gq * 128 + wr * 64 + 32 + li) * 8];     \
    bf16x8 a3 = *(const bf16x8*)&As[BB][(gq * 128 + wr * 64 + 48 + li) * 8];     \
    bf16x8 g0 = *(const bf16x8*)&Bg[BB][(gq * 64 + wc * 32 +      li) * 8];      \
    bf16x8 g1 = *(const bf16x8*)&Bg[BB][(gq * 64 + wc * 32 + 16 + li) * 8];      \
    bf16x8 u0 = *(const bf16x8*)&Bu[BB][(gq * 64 + wc * 32 +      li) * 8];      \
    bf16x8 u1 = *(const bf16x8*)&Bu[BB][(gq * 64 + wc * 32 + 16 + li) * 8];      \
    ag[0][0] = __builtin_amdgcn_mfma_f32_16x16x32_bf16(a0, g0, ag[0][0], 0, 0, 0); \
    ag[1][0] = __builtin_amdgcn_mfma_f32_16x16x32_bf16(a1, g0, ag[1][0], 0, 0, 0); \
    ag[2][0] = __builtin_amdgcn_mfma_f32_16x16x32_bf16(a2, g0, ag[2][0], 0, 0, 0); \
    ag[3][0] = __builtin_amdgcn_mfma_f32_16x16x32_bf16(a3, g0, ag[3][0], 0, 0, 0); \
    ag[0][1] = __builtin_amdgcn_mfma_f32_16x16x32_bf16(a0, g1, ag[0][1], 0, 0, 0); \
    ag[1][1] = __builtin_amdgcn_mfma_f32_16x16x32_bf16(a1, g1, ag[1][1], 0, 0, 0); \
    ag[2][1] = __builtin_amdgcn_mfma_f32_16x16x32_bf16(a2, g1, ag[2][1], 0, 0, 0); \
    ag[3][1] = __builtin_amdgcn_mfma_f32_16x16x32_bf16(a3, g1, ag[3][1], 0, 0, 0); \
    au[0][0] = __builtin_amdgcn_mfma_f32_16x16x32_bf16(a0, u0, au[0][0], 0, 0, 0); \
    au[1][0] = __builtin_amdgcn_mfma_f32_16x16x32_bf16(a1, u0, au[1][0], 0, 0, 0); \
    au[2][0] = __builtin_amdgcn_mfma_f32_16x16x32_bf16(a2, u0, au[2][0], 0, 0, 0); \
    au[3][0] = __builtin_amdgcn_mfma_f32_16x16x32_bf16(a3, u0, au[3][0], 0, 0, 0); \
    au[0][1] = __builtin_amdgcn_mfma_f32_16x16x32_bf16(a0, u1, au[0][1], 0, 0, 0); \
    au[1][1] = __builtin_amdgcn_mfma_f32_16x16x32_bf16(a1, u1, au[1][1], 0, 0, 0); \
    au[2][1] = __builtin_amdgcn_mfma_f32_16x16x32_bf16(a2, u1, au[2][1], 0, 0, 0); \
    au[3][1] = __builtin_amdgcn_mfma_f32_16x16x32_bf16(a3, u1, au[3][1], 0, 0, 0); \
  }

  M1_ISSUE(0, 0); M1_ISSUE(1, 1); M1_ISSUE(2, 2);

  for (int jc = 0; jc < 15; ++jc) {
    const int j = jc * 4;
    VMW(8); BARF; M1_ISSUE(j + 3, 3); M1_MFMA(0);
    VMW(8); BARF; M1_ISSUE(j + 4, 0); M1_MFMA(1);
    VMW(8); BARF; M1_ISSUE(j + 5, 1); M1_MFMA(2);
    VMW(8); BARF; M1_ISSUE(j + 6, 2); M1_MFMA(3);
  }
  VMW(8); BARF; M1_ISSUE(63, 3); M1_MFMA(0);
  VMW(8); BARF;                  M1_MFMA(1);
  VMW(4); BARF;                  M1_MFMA(2);
  VMW(0); BARF;                  M1_MFMA(3);

#undef M1_ISSUE
#undef M1_MFMA

  // epilogue: h = silu(g)*u, written in packed cell layout hP[e][i>>3][slot][i&7]
  u16* hPe = hP + (size_t)e * 786432;            // 96*8192
  #pragma unroll
  for (int mf = 0; mf < 4; ++mf) {
    #pragma unroll
    for (int j = 0; j < 4; ++j) {
      const int slot = m0 + wr * 64 + mf * 16 + gq * 4 + j;
      #pragma unroll
      for (int nf = 0; nf < 2; ++nf) {
        const int ii = n0 + wc * 32 + nf * 16 + li;
        float gg = ag[mf][nf][j];
        float uu = au[mf][nf][j];
        hPe[(size_t)(ii >> 3) * 8192 + slot * 8 + (ii & 7)] =
            f2b(gg * uu / (1.f + __expf(-gg)));
      }
    }
  }
}

// down GEMM + weighted scatter-add. grid 8192 XCD-swizzled.
__global__ __launch_bounds__(256, 2) void k_mlp2p(
    const u16* __restrict__ hP, const u16* __restrict__ Dpk,
    const int* __restrict__ counts, const int* __restrict__ slot_token,
    const float* __restrict__ slot_w, float* __restrict__ out)
{
  const int i   = blockIdx.x;
  const int xcd = i & 7;
  const int p   = i >> 3;
  const int mt  = p & 7;
  const int pe  = p >> 3;
  const int val = pe * 8 + xcd;    // == e*16 + nt
  const int e   = val >> 4;
  const int nt  = val & 15;

  int cnt = counts[e]; if (cnt > CAP) cnt = CAP;
  const int m0 = mt * 128;
  if (m0 >= cnt) return;
  const int n0 = nt * 128;

  const int t = threadIdx.x;
  const int lane = t & 63, wv = t >> 6;
  const int li = lane & 15, gq = lane >> 4;
  const int wm = (wv >> 1) * 64, wn = (wv & 1) * 64;

  __shared__ u16 As[4][4 * 128 * 8];   // 32 KB
  __shared__ u16 Bt[4][4 * 128 * 8];   // 32 KB

  const u16* hPe = hP + (size_t)e * 786432;
  const u16* dp0 = Dpk + (size_t)e * 1572864 + (size_t)(nt * 2) * 49152;
  const u16* dp1 = dp0 + 49152;

  f32x4 acc[4][4];
  #pragma unroll
  for (int m = 0; m < 4; ++m)
    #pragma unroll
    for (int n = 0; n < 4; ++n) { f32x4 z = {0.f,0.f,0.f,0.f}; acc[m][n] = z; }

#define M2_ISSUE(JS, SB)                                                    \
  {                                                                         \
    const size_t cell = (size_t)(JS) * 4 + wv;                              \
    glp16(hPe + cell * 8192 + (m0 + lane) * 8,      &As[SB][(wv * 128) * 8]);      \
    glp16(hPe + cell * 8192 + (m0 + 64 + lane) * 8, &As[SB][(wv * 128 + 64) * 8]); \
    glp16(dp0 + cell * 512 + lane * 8, &Bt[SB][(wv * 128) * 8]);            \
    glp16(dp1 + cell * 512 + lane * 8, &Bt[SB][(wv * 128 + 64) * 8]);       \
  }

#define M2_MFMA(BB)                                                                \
  {                                                                                \
    bf16x8 a0 = *(const bf16x8*)&As[BB][(gq * 128 + wm +      li) * 8];            \
    bf16x8 a1 = *(const bf16x8*)&As[BB][(gq * 128 + wm + 16 + li) * 8];            \
    bf16x8 a2 = *(const bf16x8*)&As[BB][(gq * 128 + wm + 32 + li) * 8];            \
    bf16x8 a3 = *(const bf16x8*)&As[BB][(gq * 128 + wm + 48 + li) * 8];            \
    bf16x8 b0 = *(const bf16x8*)&Bt[BB][(gq * 128 + wn +      li) * 8];            \
    bf16x8 b1 = *(const bf16x8*)&Bt[BB][(gq * 128 + wn + 16 + li) * 8];            \
    bf16x8 b2 = *(const bf16x8*)&Bt[BB][(gq * 128 + wn + 32 + li) * 8];            \
    bf16x8 b3 = *(const bf16x8*)&Bt[BB][(gq * 128 + wn + 48 + li) * 8];            \
    acc[0][0] = __builtin_amdgcn_mfma_f32_16x16x32_bf16(a0, b0, acc[0][0], 0, 0, 0); \
    acc[0][1] = __builtin_amdgcn_mfma_f32_16x16x32_bf16(a0, b1, acc[0][1], 0, 0, 0); \
    acc[0][2] = __builtin_amdgcn_mfma_f32_16x16x32_bf16(a0, b2, acc[0][2], 0, 0, 0); \
    acc[0][3] = __builtin_amdgcn_mfma_f32_16x16x32_bf16(a0, b3, acc[0][3], 0, 0, 0); \
    acc[1][0] = __builtin_amdgcn_mfma_f32_16x16x32_bf16(a1, b0, acc[1][0], 0, 0, 0); \
    acc[1][1] = __builtin_amdgcn_mfma_f32_16x16x32_bf16(a1, b1, acc[1][1], 0, 0, 0); \
    acc[1][2] = __builtin_amdgcn_mfma_f32_16x16x32_bf16(a1, b2, acc[1][2], 0, 0, 0); \
    acc[1][3] = __builtin_amdgcn_mfma_f32_16x16x32_bf16(a1, b3, acc[1][3], 0, 0, 0); \
    acc[2][0] = __builtin_amdgcn_mfma_f32_16x16x32_bf16(a2, b0, acc[2][0], 0, 0, 0); \
    acc[2][1] = __builtin_amdgcn_mfma_f32_16x16x32_bf16(a2, b1, acc[2][1], 0, 0, 0); \
    acc[2][2] = __builtin_amdgcn_mfma_f32_16x16x32_bf16(a2, b2, acc[2][2], 0, 0, 0); \
    acc[2][3] = __builtin_amdgcn_mfma_f32_16x16x32_bf16(a2, b3, acc[2][3], 0, 0, 0); \
    acc[3][0] = __builtin_amdgcn_mfma_f32_16x16x32_bf16(a3, b0, acc[3][0], 0, 0, 0); \
    acc[3][1] = __builtin_amdgcn_mfma_f32_16x16x32_bf16(a3, b1, acc[3][1], 0, 0, 0); \
    acc[3][2] = __builtin_amdgcn_mfma_f32_16x16x32_bf16(a3, b2, acc[3][2], 0, 0, 0); \
    acc[3][3] = __builtin_amdgcn_mfma_f32_16x16x32_bf16(a3, b3, acc[3][3], 0, 0, 0); \
  }

  M2_ISSUE(0, 0); M2_ISSUE(1, 1); M2_ISSUE(2, 2);

  for (int jc = 0; jc < 5; ++jc) {
    const int j = jc * 4;
    VMW(8); BARF; M2_ISSUE(j + 3, 3); M2_MFMA(0);
    VMW(8); BARF; M2_ISSUE(j + 4, 0); M2_MFMA(1);
    VMW(8); BARF; M2_ISSUE(j + 5, 1); M2_MFMA(2);
    VMW(8); BARF; M2_ISSUE(j + 6, 2); M2_MFMA(3);
  }
  VMW(8); BARF; M2_ISSUE(23, 3); M2_MFMA(0);
  VMW(8); BARF;                  M2_MFMA(1);
  VMW(4); BARF;                  M2_MFMA(2);
  VMW(0); BARF;                  M2_MFMA(3);

#undef M2_ISSUE
#undef M2_MFMA

  #pragma unroll
  for (int mf = 0; mf < 4; ++mf) {
    #pragma unroll
    for (int j = 0; j < 4; ++j) {
      const int slot = m0 + wm + mf * 16 + gq * 4 + j;
      if (slot < cnt) {
        const int   tk  = slot_token[e * CAP + slot];
        const float wgt = slot_w[e * CAP + slot];
        float* orow = out + (size_t)tk * D_DIM + n0 + wn + li;
        #pragma unroll
        for (int nf = 0; nf < 4; ++nf)
          atomicAdd(&orow[nf * 16], wgt * acc[mf][nf][j]);
      }
    }
  }
}

// ================= mid fallback path (round-7 kernels, ws >= 722MB) ===========

__global__ __launch_bounds__(256) void k_cvt_t(const float* __restrict__ in,
                                               u16* __restrict__ outp,
                                               int R, int C) {
  const int e  = blockIdx.z;
  const int c0 = blockIdx.x * 64;
  const int r0 = blockIdx.y * 64;
  const float* ip = in + (size_t)e * R * C;
  u16* op = outp + (size_t)e * R * C;

  __shared__ u16 T[64][72];
  const int t  = threadIdx.x;
  const int rr = t >> 4;
  const int cc = (t & 15) * 4;
  #pragma unroll
  for (int it = 0; it < 4; ++it) {
    const int r = rr + it * 16;
    float4 v = *(const float4*)(ip + (size_t)(r0 + r) * C + c0 + cc);
    T[cc + 0][r] = f2b(v.x);
    T[cc + 1][r] = f2b(v.y);
    T[cc + 2][r] = f2b(v.z);
    T[cc + 3][r] = f2b(v.w);
  }
  __syncthreads();
  const int cw = t >> 3;
  const int r8 = (t & 7) * 8;
  #pragma unroll
  for (int jt = 0; jt < 2; ++jt) {
    const int c = cw + jt * 32;
    const u16* s = &T[c][r8];
    uint4 o;
    o.x = (u32)s[0] | ((u32)s[1] << 16);
    o.y = (u32)s[2] | ((u32)s[3] << 16);
    o.z = (u32)s[4] | ((u32)s[5] << 16);
    o.w = (u32)s[6] | ((u32)s[7] << 16);
    *(uint4*)(op + (size_t)(c0 + c) * R + r0 + r8) = o;
  }
}

__global__ __launch_bounds__(256, 2) void k_mlp1(
    const u16* __restrict__ xb, const u16* __restrict__ gT,
    const u16* __restrict__ uT, const int* __restrict__ counts,
    const int* __restrict__ slot_token, u16* __restrict__ h)
{
  const int i   = blockIdx.x;
  const int xcd = i & 7;
  const int p   = i >> 3;
  const int mt  = p & 7;
  const int pe  = p >> 3;
  const int val = pe * 8 + xcd;
  const int e   = val / 12;
  const int nt  = val % 12;

  int cnt = counts[e]; if (cnt > CAP) cnt = CAP;
  const int m0 = mt * 128;
  if (m0 >= cnt) return;
  const int n0 = nt * 64;

  const int t = threadIdx.x;
  const int lane = t & 63, wv = t >> 6;
  const int li = lane & 15, gq = lane >> 4;
  const int wr = wv >> 1, wc = wv & 1;

  __shared__ u16 As[4][4 * 128 * 8];
  __shared__ u16 Bg[4][4 * 64 * 8];
  __shared__ u16 Bu[4][4 * 64 * 8];

  const int tok0 = slot_token[e * CAP + m0 + lane];
  const int tok1 = slot_token[e * CAP + m0 + 64 + lane];
  const u16* xr0 = xb + (size_t)tok0 * D_DIM;
  const u16* xr1 = xb + (size_t)tok1 * D_DIM;
  const u16* gb  = gT + (size_t)e * D_DIM * I_DIM + (size_t)(n0 + lane) * D_DIM;
  const u16* ub  = uT + (size_t)e * D_DIM * I_DIM + (size_t)(n0 + lane) * D_DIM;

  f32x4 ag[4][2], au[4][2];
  #pragma unroll
  for (int m = 0; m < 4; ++m)
    #pragma unroll
    for (int n = 0; n < 2; ++n) {
      f32x4 z = {0.f, 0.f, 0.f, 0.f};
      ag[m][n] = z; au[m][n] = z;
    }

#define F1_ISSUE(JS, SB)                                           \
  {                                                                \
    const int kks = (JS) * 32;                                     \
    glp16(xr0 + kks + wv * 8, &As[SB][(wv * 128) * 8]);            \
    glp16(xr1 + kks + wv * 8, &As[SB][(wv * 128 + 64) * 8]);       \
    glp16(gb  + kks + wv * 8, &Bg[SB][(wv * 64) * 8]);             \
    glp16(ub  + kks + wv * 8, &Bu[SB][(wv * 64) * 8]);             \
  }

#define F1_MFMA(BB)                                                              \
  {                                                                              \
    bf16x8 a0 = *(const bf16x8*)&As[BB][(gq * 128 + wr * 64 +      li) * 8];     \
    bf16x8 a1 = *(const bf16x8*)&As[BB][(gq * 128 + wr * 64 + 16 + li) * 8];     \
    bf16x8 a2 = *(const bf16x8*)&As[BB][(gq * 128 + wr * 64 + 32 + li) * 8];     \
    bf16x8 a3 = *(const bf16x8*)&As[BB][(gq * 128 + wr * 64 + 48 + li) * 8];     \
    bf16x8 g0 = *(const bf16x8*)&Bg[BB][(gq * 64 + wc * 32 +      li) * 8];      \
    bf16x8 g1 = *(const bf16x8*)&Bg[BB][(gq * 64 + wc * 32 + 16 + li) * 8];      \
    bf16x8 u0 = *(const bf16x8*)&Bu[BB][(gq * 64 + wc * 32 +      li) * 8];      \
    bf16x8 u1 = *(const bf16x8*)&Bu[BB][(gq * 64 + wc * 32 + 16 + li) * 8];      \
    ag[0][0] = __builtin_amdgcn_mfma_f32_16x16x32_bf16(a0, g0, ag[0][0], 0, 0, 0); \
    ag[1][0] = __builtin_amdgcn_mfma_f32_16x16x32_bf16(a1, g0, ag[1][0], 0, 0, 0); \
    ag[2][0] = __builtin_amdgcn_mfma_f32_16x16x32_bf16(a2, g0, ag[2][0], 0, 0, 0); \
    ag[3][0] = __builtin_amdgcn_mfma_f32_16x16x32_bf16(a3, g0, ag[3][0], 0, 0, 0); \
    ag[0][1] = __builtin_amdgcn_mfma_f32_16x16x32_bf16(a0, g1, ag[0][1], 0, 0, 0); \
    ag[1][1] = __builtin_amdgcn_mfma_f32_16x16x32_bf16(a1, g1, ag[1][1], 0, 0, 0); \
    ag[2][1] = __builtin_amdgcn_mfma_f32_16x16x32_bf16(a2, g1, ag[2][1], 0, 0, 0); \
    ag[3][1] = __builtin_amdgcn_mfma_f32_16x16x32_bf16(a3, g1, ag[3][1], 0, 0, 0); \
    au[0][0] = __builtin_amdgcn_mfma_f32_16x16x32_bf16(a0, u0, au[0][0], 0, 0, 0); \
    au[1][0] = __builtin_amdgcn_mfma_f32_16x16x32_bf16(a1, u0, au[1][0], 0, 0, 0); \
    au[2][0] = __builtin_amdgcn_mfma_f32_16x16x32_bf16(a2, u0, au[2][0], 0, 0, 0); \
    au[3][0] = __builtin_amdgcn_mfma_f32_16x16x32_bf16(a3, u0, au[3][0], 0, 0, 0); \
    au[0][1] = __builtin_amdgcn_mfma_f32_16x16x32_bf16(a0, u1, au[0][1], 0, 0, 0); \
    au[1][1] = __builtin_amdgcn_mfma_f32_16x16x32_bf16(a1, u1, au[1][1], 0, 0, 0); \
    au[2][1] = __builtin_amdgcn_mfma_f32_16x16x32_bf16(a2, u1, au[2][1], 0, 0, 0); \
    au[3][1] = __builtin_amdgcn_mfma_f32_16x16x32_bf16(a3, u1, au[3][1], 0, 0, 0); \
  }

  F1_ISSUE(0, 0); F1_ISSUE(1, 1); F1_ISSUE(2, 2);
  for (int jc = 0; jc < 15; ++jc) {
    const int j = jc * 4;
    VMW(8); BARF; F1_ISSUE(j + 3, 3); F1_MFMA(0);
    VMW(8); BARF; F1_ISSUE(j + 4, 0); F1_MFMA(1);
    VMW(8); BARF; F1_ISSUE(j + 5, 1); F1_MFMA(2);
    VMW(8); BARF; F1_ISSUE(j + 6, 2); F1_MFMA(3);
  }
  VMW(8); BARF; F1_ISSUE(63, 3); F1_MFMA(0);
  VMW(8); BARF;                  F1_MFMA(1);
  VMW(4); BARF;                  F1_MFMA(2);
  VMW(0); BARF;                  F1_MFMA(3);
#undef F1_ISSUE
#undef F1_MFMA

  #pragma unroll
  for (int mf = 0; mf < 4; ++mf) {
    #pragma unroll
    for (int j = 0; j < 4; ++j) {
      const int slot = m0 + wr * 64 + mf * 16 + gq * 4 + j;
      u16* hr = h + (size_t)(e * CAP + slot) * I_DIM + n0 + wc * 32 + li;
      #pragma unroll
      for (int nf = 0; nf < 2; ++nf) {
        float gg = ag[mf][nf][j];
        float uu = au[mf][nf][j];
        hr[nf * 16] = f2b(gg * uu / (1.f + __expf(-gg)));
      }
    }
  }
}

__global__ __launch_bounds__(256, 2) void k_mlp2(
    const u16* __restrict__ h, const u16* __restrict__ dT,
    const int* __restrict__ counts, const int* __restrict__ slot_token,
    const float* __restrict__ slot_w, float* __restrict__ out)
{
  const int i   = blockIdx.x;
  const int xcd = i & 7;
  const int p   = i >> 3;
  const int mt  = p & 7;
  const int pe  = p >> 3;
  const int val = pe * 8 + xcd;
  const int e   = val >> 4;
  const int nt  = val & 15;

  int cnt = counts[e]; if (cnt > CAP) cnt = CAP;
  const int m0 = mt * 128;
  if (m0 >= cnt) return;
  const int n0 = nt * 128;

  const int t = threadIdx.x;
  const int lane = t & 63, wv = t >> 6;
  const int li = lane & 15, gq = lane >> 4;
  const int wm = (wv >> 1) * 64, wn = (wv & 1) * 64;

  __shared__ u16 As[4][4 * 128 * 8];
  __shared__ u16 Bt[4][4 * 128 * 8];

  const u16* hr0 = h + (size_t)(e * CAP + m0 + lane) * I_DIM;
  const u16* hr1 = h + (size_t)(e * CAP + m0 + 64 + lane) * I_DIM;
  const u16* dr0 = dT + (size_t)e * I_DIM * D_DIM + (size_t)(n0 + lane) * I_DIM;
  const u16* dr1 = dT + (size_t)e * I_DIM * D_DIM + (size_t)(n0 + 64 + lane) * I_DIM;

  f32x4 acc[4][4];
  #pragma unroll
  for (int m = 0; m < 4; ++m)
    #pragma unroll
    for (int n = 0; n < 4; ++n) { f32x4 z = {0.f,0.f,0.f,0.f}; acc[m][n] = z; }

#define F2_ISSUE(JS, SB)                                           \
  {                                                                \
    const int kks = (JS) * 32;                                     \
    glp16(hr0 + kks + wv * 8, &As[SB][(wv * 128) * 8]);            \
    glp16(hr1 + kks + wv * 8, &As[SB][(wv * 128 + 64) * 8]);       \
    glp16(dr0 + kks + wv * 8, &Bt[SB][(wv * 128) * 8]);            \
    glp16(dr1 + kks + wv * 8, &Bt[SB][(wv * 128 + 64) * 8]);       \
  }

#define F2_MFMA(BB)                                                                \
  {                                                                                \
    bf16x8 a0 = *(const bf16x8*)&As[BB][(gq * 128 + wm +      li) * 8];            \
    bf16x8 a1 = *(const bf16x8*)&As[BB][(gq * 128 + wm + 16 + li) * 8];            \
    bf16x8 a2 = *(const bf16x8*)&As[BB][(gq * 128 + wm + 32 + li) * 8];            \
    bf16x8 a3 = *(const bf16x8*)&As[BB][(gq * 128 + wm + 48 + li) * 8];            \
    bf16x8 b0 = *(const bf16x8*)&Bt[BB][(gq * 128 + wn +      li) * 8];            \
    bf16x8 b1 = *(const bf16x8*)&Bt[BB][(gq * 128 + wn + 16 + li) * 8];            \
    bf16x8 b2 = *(const bf16x8*)&Bt[BB][(gq * 128 + wn + 32 + li) * 8];            \
    bf16x8 b3 = *(const bf16x8*)&Bt[BB][(gq * 128 + wn + 48 + li) * 8];            \
    acc[0][0] = __builtin_amdgcn_mfma_f32_16x16x32_bf16(a0, b0, acc[0][0], 0, 0, 0); \
    acc[0][1] = __builtin_amdgcn_mfma_f32_16x16x32_bf16(a0, b1, acc[0][1], 0, 0, 0); \
    acc[0][2] = __builtin_amdgcn_mfma_f32_16x16x32_bf16(a0, b2, acc[0][2], 0, 0, 0); \
    acc[0][3] = __builtin_amdgcn_mfma_f32_16x16x32_bf16(a0, b3, acc[0][3], 0, 0, 0); \
    acc[1][0] = __builtin_amdgcn_mfma_f32_16x16x32_bf16(a1, b0, acc[1][0], 0, 0, 0); \
    acc[1][1] = __builtin_amdgcn_mfma_f32_16x16x32_bf16(a1, b1, acc[1][1], 0, 0, 0); \
    acc[1][2] = __builtin_amdgcn_mfma_f32_16x16x32_bf16(a1, b2, acc[1][2], 0, 0, 0); \
    acc[1][3] = __builtin_amdgcn_mfma_f32_16x16x32_bf16(a1, b3, acc[1][3], 0, 0, 0); \
    acc[2][0] = __builtin_amdgcn_mfma_f32_16x16x32_bf16(a2, b0, acc[2][0], 0, 0, 0); \
    acc[2][1] = __builtin_amdgcn_mfma_f32_16x16x32_bf16(a2, b1, acc[2][1], 0, 0, 0); \
    acc[2][2] = __builtin_amdgcn_mfma_f32_16x16x32_bf16(a2, b2, acc[2][2], 0, 0, 0); \
    acc[2][3] = __builtin_amdgcn_mfma_f32_16x16x32_bf16(a2, b3, acc[2][3], 0, 0, 0); \
    acc[3][0] = __builtin_amdgcn_mfma_f32_16x16x32_bf16(a3, b0, acc[3][0], 0, 0, 0); \
    acc[3][1] = __builtin_amdgcn_mfma_f32_16x16x32_bf16(a3, b1, acc[3][1], 0, 0, 0); \
    acc[3][2] = __builtin_amdgcn_mfma_f32_16x16x32_bf16(a3, b2, acc[3][2], 0, 0, 0); \
    acc[3][3] = __builtin_amdgcn_mfma_f32_16x16x32_bf16(a3, b3, acc[3][3], 0, 0, 0); \
  }

  F2_ISSUE(0, 0); F2_ISSUE(1, 1); F2_ISSUE(2, 2);
  for (int jc = 0; jc < 5; ++jc) {
    const int j = jc * 4;
    VMW(8); BARF; F2_ISSUE(j + 3, 3); F2_MFMA(0);
    VMW(8); BARF; F2_ISSUE(j + 4, 0); F2_MFMA(1);
    VMW(8); BARF; F2_ISSUE(j + 5, 1); F2_MFMA(2);
    VMW(8); BARF; F2_ISSUE(j + 6, 2); F2_MFMA(3);
  }
  VMW(8); BARF; F2_ISSUE(23, 3); F2_MFMA(0);
  VMW(8); BARF;                  F2_MFMA(1);
  VMW(4); BARF;                  F2_MFMA(2);
  VMW(0); BARF;                  F2_MFMA(3);
#undef F2_ISSUE
#undef F2_MFMA

  #pragma unroll
  for (int mf = 0; mf < 4; ++mf) {
    #pragma unroll
    for (int j = 0; j < 4; ++j) {
      const int slot = m0 + wm + mf * 16 + gq * 4 + j;
      if (slot < cnt) {
        const int   tk  = slot_token[e * CAP + slot];
        const float wgt = slot_w[e * CAP + slot];
        float* orow = out + (size_t)tk * D_DIM + n0 + wn + li;
        #pragma unroll
        for (int nf = 0; nf < 4; ++nf)
          atomicAdd(&orow[nf * 16], wgt * acc[mf][nf][j]);
      }
    }
  }
}

extern "C" void kernel_launch(void* const* d_in, const int* in_sizes, int n_in,
                              void* d_out, int out_size, void* d_ws, size_t ws_size,
                              hipStream_t stream) {
  const float* x    = (const float*)d_in[0];
  const float* rw   = (const float*)d_in[1];
  const float* gate = (const float*)d_in[2];
  const float* up   = (const float*)d_in[3];
  const float* down = (const float*)d_in[4];
  float* out = (float*)d_out;

  char* ws = (char*)d_ws;
  int*   counts     = (int*)ws;
  int*   slot_token = (int*)(ws + 1024);
  float* slot_w     = (float*)(ws + 263168);
  u16*   xb         = (u16*)(ws + 525312);
  u16*   hP         = (u16*)(ws + 17302528);          // 100.66 MB (both paths)
  u16*   Gpk        = (u16*)(ws + 117965824);         // 201.3 MB
  u16*   Upk        = (u16*)(ws + 319292416);         // 201.3 MB
  u16*   xeT        = (u16*)(ws + 520619008);         // 268.4 MB (packed path)
  u16*   Dpk        = xeT;                            // aliased: written after mlp1
  const bool packed = ws_size >= 789054464ull;
  const bool mid    = ws_size >= 721945600ull;

  hipMemsetAsync(counts, 0, NE * sizeof(int), stream);
  hipMemsetAsync(slot_token, 0, (size_t)NE * CAP * sizeof(int), stream);
  hipMemsetAsync(out, 0, (size_t)out_size * sizeof(float), stream);

  k_cvt_x <<<dim3((NTOK * D_DIM) / (256 * 8)), 256, 0, stream>>>(x, xb);
  k_router<<<dim3(NTOK / 4),                   256, 0, stream>>>(x, rw, counts, slot_token, slot_w);

  if (packed) {
    k_wpack<<<dim3(12, 32, NE), 256, 0, stream>>>(gate, Gpk, D_DIM, I_DIM);
    k_wpack<<<dim3(12, 32, NE), 256, 0, stream>>>(up,   Upk, D_DIM, I_DIM);
    k_xpack<<<dim3(8, 16, NE),  256, 0, stream>>>(xb, counts, slot_token, xeT);
    k_mlp1p<<<dim3(6144), 256, 0, stream>>>(xeT, Gpk, Upk, counts, hP);
    k_wpack<<<dim3(32, 12, NE), 256, 0, stream>>>(down, Dpk, I_DIM, D_DIM);  // aliases xeT
    k_mlp2p<<<dim3(8192), 256, 0, stream>>>(hP, Dpk, counts, slot_token, slot_w, out);
  } else if (mid) {
    // round-7 layout: gT/uT/dT as plain [e][C][R] bf16 transposes
    u16* gT = Gpk;
    u16* uT = Upk;
    u16* dT = (u16*)(ws + 520619008);
    k_cvt_t<<<dim3(12, 32, NE), 256, 0, stream>>>(gate, gT, D_DIM, I_DIM);
    k_cvt_t<<<dim3(12, 32, NE), 256, 0, stream>>>(up,   uT, D_DIM, I_DIM);
    k_cvt_t<<<dim3(32, 12, NE), 256, 0, stream>>>(down, dT, I_DIM, D_DIM);
    k_mlp1<<<dim3(6144), 256, 0, stream>>>(xb, gT, uT, counts, slot_token, hP);
    k_mlp2<<<dim3(8192), 256, 0, stream>>>(hP, dT, counts, slot_token, slot_w, out);
  }
}

// Round 9
// 1347.114 us; speedup vs baseline: 1.4842x; 1.2120x over previous
//
#include <hip/hip_runtime.h>
#include <hip/hip_bf16.h>

typedef __attribute__((ext_vector_type(4))) float f32x4;
typedef __attribute__((ext_vector_type(8))) short bf16x8;
typedef __attribute__((ext_vector_type(8))) unsigned short us8;
typedef unsigned int   u32;
typedef unsigned short u16;

#define D_DIM 2048
#define I_DIM 768
#define NE    64
#define CAP   1024
#define NTOK  4096

__device__ __forceinline__ u32 cvt2(float a, float b) {
  __hip_bfloat162 hh = __float22bfloat162_rn(float2{a, b});
  union { __hip_bfloat162 h; u32 u; } c; c.h = hh; return c.u;
}
__device__ __forceinline__ u16 f2b(float f) {
  __hip_bfloat16 b = __float2bfloat16(f);
  union { __hip_bfloat16 b; u16 u; } c; c.b = b; return c.u;
}
// async global->LDS, 16B per lane. LDS dest = wave-uniform base + lane*16.
__device__ __forceinline__ void glp16(const void* g, void* l) {
  __builtin_amdgcn_global_load_lds(
      (const __attribute__((address_space(1))) u32*)g,
      (__attribute__((address_space(3))) u32*)l, 16, 0, 0);
}

#define VMW(n) asm volatile("s_waitcnt vmcnt(" #n ")" ::: "memory")
#define BARF   do { __builtin_amdgcn_s_barrier(); \
                    asm volatile("" ::: "memory"); } while (0)

// ---------------- x fp32 -> bf16 ----------------
__global__ __launch_bounds__(256) void k_cvt_x(const float* __restrict__ x,
                                               u16* __restrict__ xb) {
  const size_t i = ((size_t)blockIdx.x * 256 + threadIdx.x) * 8;
  float4 v0 = *(const float4*)(x + i);
  float4 v1 = *(const float4*)(x + i + 4);
  uint4 o;
  o.x = cvt2(v0.x, v0.y); o.y = cvt2(v0.z, v0.w);
  o.z = cvt2(v1.x, v1.y); o.w = cvt2(v1.z, v1.w);
  *(uint4*)(xb + i) = o;
}

// ---------------- router: fp32 logits, top-8, renorm, dispatch ----------------
__global__ __launch_bounds__(256) void k_router(
    const float* __restrict__ x, const float* __restrict__ rw,
    int* __restrict__ counts, int* __restrict__ slot_token,
    float* __restrict__ slot_w)
{
  const int lane = threadIdx.x & 63;
  const int tok  = blockIdx.x * 4 + (threadIdx.x >> 6);
  const float* xr = x + (size_t)tok * D_DIM;

  float acc = 0.f;
  for (int d0 = 0; d0 < D_DIM; d0 += 64) {
    float xv = xr[d0 + lane];
    #pragma unroll
    for (int j = 0; j < 64; ++j) {
      float xj = __shfl(xv, j, 64);
      acc = fmaf(xj, rw[(size_t)(d0 + j) * NE + lane], acc);
    }
  }

  float v = acc; int vi = lane;
  float wk[8]; int ei[8];
  float mx0 = 0.f, wsum = 0.f;
  #pragma unroll
  for (int k = 0; k < 8; ++k) {
    float mv = v; int mi = vi;
    #pragma unroll
    for (int off = 32; off >= 1; off >>= 1) {
      float ov = __shfl_xor(mv, off, 64);
      int   oi = __shfl_xor(mi, off, 64);
      if (ov > mv || (ov == mv && oi < mi)) { mv = ov; mi = oi; }
    }
    if (k == 0) mx0 = mv;
    float ew = __expf(mv - mx0);
    wk[k] = ew; ei[k] = mi; wsum += ew;
    if (lane == mi) v = -3.4e38f;
  }

  if (lane == 0) {
    float inv = 1.f / wsum;
    #pragma unroll
    for (int k = 0; k < 8; ++k) {
      int ee   = ei[k];
      int slot = atomicAdd(&counts[ee], 1);
      if (slot < CAP) {
        slot_token[ee * CAP + slot] = tok;
        slot_w[ee * CAP + slot]     = wk[k] * inv;
      }
    }
  }
}

// ---------------- weight pack: fp32 [R][C] -> bf16 [C/64][R/8][64][8] per e ----
__global__ __launch_bounds__(256) void k_wpack(const float* __restrict__ in,
                                               u16* __restrict__ outp,
                                               int R, int C) {
  const int e  = blockIdx.z;
  const int c0 = blockIdx.x * 64;
  const int r0 = blockIdx.y * 64;
  const float* ip = in + (size_t)e * R * C;
  u16* op = outp + (size_t)e * (size_t)(C / 64) * (R / 8) * 512
                 + ((size_t)(c0 / 64) * (R / 8) + (r0 / 8)) * 512;

  __shared__ u16 T[64][76];     // T[n][k]
  const int t  = threadIdx.x;
  const int rr = t >> 4;        // 0..15 (k)
  const int cc = (t & 15) * 4;  // 0..60 (n)
  #pragma unroll
  for (int it = 0; it < 4; ++it) {
    const int r = rr + it * 16;
    float4 v = *(const float4*)(ip + (size_t)(r0 + r) * C + c0 + cc);
    T[cc + 0][r] = f2b(v.x);
    T[cc + 1][r] = f2b(v.y);
    T[cc + 2][r] = f2b(v.z);
    T[cc + 3][r] = f2b(v.w);
  }
  __syncthreads();
  const int n = t & 63;
  #pragma unroll
  for (int p = 0; p < 2; ++p) {
    const int c = (t >> 6) + p * 4;           // kcell 0..7
    const u16* s = &T[n][c * 8];
    uint4 o;
    o.x = (u32)s[0] | ((u32)s[1] << 16);
    o.y = (u32)s[2] | ((u32)s[3] << 16);
    o.z = (u32)s[4] | ((u32)s[5] << 16);
    o.w = (u32)s[6] | ((u32)s[7] << 16);
    *(uint4*)(op + ((size_t)c * 64 + n) * 8) = o;
  }
}

// ---------------- x pack: gather tokens -> xeT[e][kcell(256)][1024][8] --------
__global__ __launch_bounds__(256) void k_xpack(
    const u16* __restrict__ xb, const int* __restrict__ counts,
    const int* __restrict__ slot_token, u16* __restrict__ xeT)
{
  const int e   = blockIdx.z;
  const int s0  = blockIdx.y * 64;
  const int kc0 = blockIdx.x * 32;
  int cnt = counts[e]; if (cnt > CAP) cnt = CAP;

  __shared__ u16 T[64][264];
  const int t = threadIdx.x;
  const int r = t >> 2;
  const int q = t & 3;
  const int  tok  = slot_token[e * CAP + s0 + r];
  const bool live = (s0 + r) < cnt;
  const u16* src = xb + (size_t)tok * D_DIM + kc0 * 8;

  #pragma unroll
  for (int it = 0; it < 8; ++it) {
    const int kl = it * 32 + q * 8;
    us8 v = {0, 0, 0, 0, 0, 0, 0, 0};
    if (live) v = *(const us8*)(src + kl);
    *(us8*)&T[r][kl] = v;
  }
  __syncthreads();

  u16* dst = xeT + (size_t)e * 2097152 + (size_t)kc0 * 8192 + (size_t)s0 * 8;
  const int sl = t & 63;
  #pragma unroll
  for (int p = 0; p < 8; ++p) {
    const int c = (t >> 6) + p * 4;
    const u16* s = &T[sl][c * 8];
    uint4 o = *(const uint4*)s;
    *(uint4*)(dst + (size_t)c * 8192 + sl * 8) = o;
  }
}

// ================= big-tile GEMMs: 512 thr, ring-4 128KB LDS, depth-3 vmcnt ===

// ---- mlp1 helpers: tile 256m x 128i (gate+up), wave = 64m x 64i x {g,u} ----
__device__ __forceinline__ void m1_issue(
    const u16* xeA, const u16* gbp, const u16* ubp, u16* sm,
    int js, int sb, int wv, int lane, int m0)
{
  const int st = sb * 16384;
  if (wv < 4) {
    const u16* s = xeA + (size_t)(js * 4) * 8192 + (size_t)(m0 + wv * 64 + lane) * 8;
    u16* d = sm + st + (wv * 64) * 8;
    glp16(s,         d);
    glp16(s + 8192,  d + 2048);
    glp16(s + 16384, d + 4096);
    glp16(s + 24576, d + 6144);
  } else {
    const int w2 = wv & 1;
    const u16* base = (wv >= 6) ? ubp : gbp;
    const u16* s = base + (size_t)w2 * 131072 + (size_t)(js * 4) * 512 + lane * 8;
    u16* d = sm + st + ((wv >= 6) ? 12288 : 8192) + (w2 * 64) * 8;
    glp16(s,        d);
    glp16(s + 512,  d + 1024);
    glp16(s + 1024, d + 2048);
    glp16(s + 1536, d + 3072);
  }
}

__device__ __forceinline__ void m1_step(
    const u16* sm, int st, int gq, int li, int mrow, int icol,
    f32x4 (&ag)[4][4], f32x4 (&au)[4][4])
{
  bf16x8 a[4], g[4], u[4];
  #pragma unroll
  for (int mf = 0; mf < 4; ++mf)
    a[mf] = *(const bf16x8*)&sm[st + (gq * 256 + mrow + mf * 16 + li) * 8];
  #pragma unroll
  for (int nf = 0; nf < 4; ++nf) {
    g[nf] = *(const bf16x8*)&sm[st + 8192  + (gq * 128 + icol + nf * 16 + li) * 8];
    u[nf] = *(const bf16x8*)&sm[st + 12288 + (gq * 128 + icol + nf * 16 + li) * 8];
  }
  #pragma unroll
  for (int mf = 0; mf < 4; ++mf)
    #pragma unroll
    for (int nf = 0; nf < 4; ++nf) {
      ag[mf][nf] = __builtin_amdgcn_mfma_f32_16x16x32_bf16(a[mf], g[nf], ag[mf][nf], 0, 0, 0);
      au[mf][nf] = __builtin_amdgcn_mfma_f32_16x16x32_bf16(a[mf], u[nf], au[mf][nf], 0, 0, 0);
    }
}

// grid 1536 (4mt x 6nt x 64e), XCD-swizzled, 512 threads, 128KB dynamic LDS.
__global__ __launch_bounds__(512, 2) void k_mlp1p(
    const u16* __restrict__ xeT, const u16* __restrict__ Gpk,
    const u16* __restrict__ Upk, const int* __restrict__ counts,
    u16* __restrict__ hP)
{
  extern __shared__ u16 sm[];
  const int i   = blockIdx.x;
  const int xcd = i & 7;
  const int p   = i >> 3;          // 0..191
  const int mt  = p & 3;
  const int pe  = p >> 2;          // 0..47
  const int val = pe * 8 + xcd;    // 0..383 == e*6 + nt
  const int e   = val / 6;
  const int nt  = val % 6;

  int cnt = counts[e]; if (cnt > CAP) cnt = CAP;
  const int m0 = mt * 256;
  if (m0 >= cnt) return;

  const int t = threadIdx.x;
  const int lane = t & 63, wv = t >> 6;
  const int li = lane & 15, gq = lane >> 4;
  const int mrow = (wv >> 1) * 64, icol = (wv & 1) * 64;

  const u16* xeA = xeT + (size_t)e * 2097152;
  const u16* gbp = Gpk + (size_t)e * 1572864 + (size_t)(nt * 2) * 131072;
  const u16* ubp = Upk + (size_t)e * 1572864 + (size_t)(nt * 2) * 131072;

  f32x4 ag[4][4], au[4][4];
  #pragma unroll
  for (int mf = 0; mf < 4; ++mf)
    #pragma unroll
    for (int nf = 0; nf < 4; ++nf) {
      f32x4 z = {0.f, 0.f, 0.f, 0.f};
      ag[mf][nf] = z; au[mf][nf] = z;
    }

  m1_issue(xeA, gbp, ubp, sm, 0, 0, wv, lane, m0);
  m1_issue(xeA, gbp, ubp, sm, 1, 1, wv, lane, m0);
  m1_issue(xeA, gbp, ubp, sm, 2, 2, wv, lane, m0);

  for (int j = 0; j < 61; ++j) {           // 64 K-phases total (K=2048, BK=32)
    VMW(8); BARF;
    m1_issue(xeA, gbp, ubp, sm, j + 3, (j + 3) & 3, wv, lane, m0);
    m1_step(sm, (j & 3) * 16384, gq, li, mrow, icol, ag, au);
  }
  VMW(8); BARF; m1_step(sm, 1 * 16384, gq, li, mrow, icol, ag, au);
  VMW(4); BARF; m1_step(sm, 2 * 16384, gq, li, mrow, icol, ag, au);
  VMW(0); BARF; m1_step(sm, 3 * 16384, gq, li, mrow, icol, ag, au);

  // epilogue: h = silu(g)*u, packed hP[e][i>>3][slot][i&7]
  u16* hPe = hP + (size_t)e * 786432;
  #pragma unroll
  for (int mf = 0; mf < 4; ++mf)
    #pragma unroll
    for (int jj = 0; jj < 4; ++jj) {
      const int slot = m0 + mrow + mf * 16 + gq * 4 + jj;
      #pragma unroll
      for (int nf = 0; nf < 4; ++nf) {
        const int ii = nt * 128 + icol + nf * 16 + li;
        float gg = ag[mf][nf][jj];
        float uu = au[mf][nf][jj];
        hPe[(size_t)(ii >> 3) * 8192 + slot * 8 + (ii & 7)] =
            f2b(gg * uu / (1.f + __expf(-gg)));
      }
    }
}

// ---- mlp2 helpers: tile 256m x 256n, wave = 64m x 128n ----
__device__ __forceinline__ void m2_issue(
    const u16* hPe, const u16* dpe, u16* sm,
    int js, int sb, int wv, int lane, int m0)
{
  const int st = sb * 16384;
  if (wv < 4) {
    const u16* s = hPe + (size_t)(js * 4) * 8192 + (size_t)(m0 + wv * 64 + lane) * 8;
    u16* d = sm + st + (wv * 64) * 8;
    glp16(s,         d);
    glp16(s + 8192,  d + 2048);
    glp16(s + 16384, d + 4096);
    glp16(s + 24576, d + 6144);
  } else {
    const int w2 = wv - 4;     // 0..3 -> d-col group
    const u16* s = dpe + (size_t)w2 * 49152 + (size_t)(js * 4) * 512 + lane * 8;
    u16* d = sm + st + 8192 + (w2 * 64) * 8;
    glp16(s,        d);
    glp16(s + 512,  d + 2048);
    glp16(s + 1024, d + 4096);
    glp16(s + 1536, d + 6144);
  }
}

__device__ __forceinline__ void m2_step(
    const u16* sm, int st, int gq, int li, int mrow, int ncol,
    f32x4 (&acc)[4][8])
{
  bf16x8 a[4], b[8];
  #pragma unroll
  for (int mf = 0; mf < 4; ++mf)
    a[mf] = *(const bf16x8*)&sm[st + (gq * 256 + mrow + mf * 16 + li) * 8];
  #pragma unroll
  for (int nf = 0; nf < 8; ++nf)
    b[nf] = *(const bf16x8*)&sm[st + 8192 + (gq * 256 + ncol + nf * 16 + li) * 8];
  #pragma unroll
  for (int mf = 0; mf < 4; ++mf)
    #pragma unroll
    for (int nf = 0; nf < 8; ++nf)
      acc[mf][nf] = __builtin_amdgcn_mfma_f32_16x16x32_bf16(a[mf], b[nf], acc[mf][nf], 0, 0, 0);
}

// grid 2048 (4mt x 8nt x 64e), XCD-swizzled, 512 threads, 128KB dynamic LDS.
__global__ __launch_bounds__(512, 2) void k_mlp2p(
    const u16* __restrict__ hP, const u16* __restrict__ Dpk,
    const int* __restrict__ counts, const int* __restrict__ slot_token,
    const float* __restrict__ slot_w, float* __restrict__ out)
{
  extern __shared__ u16 sm[];
  const int i   = blockIdx.x;
  const int xcd = i & 7;
  const int p   = i >> 3;          // 0..255
  const int mt  = p & 3;
  const int pe  = p >> 2;          // 0..63
  const int val = pe * 8 + xcd;    // 0..511 == e*8 + nt
  const int e   = val >> 3;
  const int nt  = val & 7;

  int cnt = counts[e]; if (cnt > CAP) cnt = CAP;
  const int m0 = mt * 256;
  if (m0 >= cnt) return;
  const int n0 = nt * 256;

  const int t = threadIdx.x;
  const int lane = t & 63, wv = t >> 6;
  const int li = lane & 15, gq = lane >> 4;
  const int mrow = (wv >> 1) * 64, ncol = (wv & 1) * 128;

  const u16* hPe = hP + (size_t)e * 786432;
  const u16* dpe = Dpk + (size_t)e * 1572864 + (size_t)(nt * 4) * 49152;

  f32x4 acc[4][8];
  #pragma unroll
  for (int mf = 0; mf < 4; ++mf)
    #pragma unroll
    for (int nf = 0; nf < 8; ++nf) { f32x4 z = {0.f,0.f,0.f,0.f}; acc[mf][nf] = z; }

  m2_issue(hPe, dpe, sm, 0, 0, wv, lane, m0);
  m2_issue(hPe, dpe, sm, 1, 1, wv, lane, m0);
  m2_issue(hPe, dpe, sm, 2, 2, wv, lane, m0);

  for (int j = 0; j < 21; ++j) {           // 24 K-phases (K=768, BK=32)
    VMW(8); BARF;
    m2_issue(hPe, dpe, sm, j + 3, (j + 3) & 3, wv, lane, m0);
    m2_step(sm, (j & 3) * 16384, gq, li, mrow, ncol, acc);
  }
  VMW(8); BARF; m2_step(sm, 1 * 16384, gq, li, mrow, ncol, acc);
  VMW(4); BARF; m2_step(sm, 2 * 16384, gq, li, mrow, ncol, acc);
  VMW(0); BARF; m2_step(sm, 3 * 16384, gq, li, mrow, ncol, acc);

  #pragma unroll
  for (int mf = 0; mf < 4; ++mf)
    #pragma unroll
    for (int jj = 0; jj < 4; ++jj) {
      const int slot = m0 + mrow + mf * 16 + gq * 4 + jj;
      if (slot < cnt) {
        const int   tk  = slot_token[e * CAP + slot];
        const float wgt = slot_w[e * CAP + slot];
        float* orow = out + (size_t)tk * D_DIM + n0 + ncol + li;
        #pragma unroll
        for (int nf = 0; nf < 8; ++nf)
          atomicAdd(&orow[nf * 16], wgt * acc[mf][nf][jj]);
      }
    }
}

extern "C" void kernel_launch(void* const* d_in, const int* in_sizes, int n_in,
                              void* d_out, int out_size, void* d_ws, size_t ws_size,
                              hipStream_t stream) {
  const float* x    = (const float*)d_in[0];
  const float* rw   = (const float*)d_in[1];
  const float* gate = (const float*)d_in[2];
  const float* up   = (const float*)d_in[3];
  const float* down = (const float*)d_in[4];
  float* out = (float*)d_out;

  char* ws = (char*)d_ws;
  int*   counts     = (int*)ws;
  int*   slot_token = (int*)(ws + 1024);
  float* slot_w     = (float*)(ws + 263168);
  u16*   xb         = (u16*)(ws + 525312);
  u16*   hP         = (u16*)(ws + 17302528);          // 100.66 MB
  u16*   Gpk        = (u16*)(ws + 117965824);         // 201.3 MB
  u16*   Upk        = (u16*)(ws + 319292416);         // 201.3 MB
  u16*   xeT        = (u16*)(ws + 520619008);         // 268.4 MB
  u16*   Dpk        = xeT;                            // aliased: written after mlp1

  // allow 128 KB dynamic LDS (host-side attr set; not a stream op, graph-safe)
  hipFuncSetAttribute((const void*)k_mlp1p,
                      hipFuncAttributeMaxDynamicSharedMemorySize, 131072);
  hipFuncSetAttribute((const void*)k_mlp2p,
                      hipFuncAttributeMaxDynamicSharedMemorySize, 131072);

  hipMemsetAsync(counts, 0, NE * sizeof(int), stream);
  hipMemsetAsync(slot_token, 0, (size_t)NE * CAP * sizeof(int), stream);
  hipMemsetAsync(out, 0, (size_t)out_size * sizeof(float), stream);

  k_cvt_x <<<dim3((NTOK * D_DIM) / (256 * 8)), 256, 0, stream>>>(x, xb);
  k_router<<<dim3(NTOK / 4),                   256, 0, stream>>>(x, rw, counts, slot_token, slot_w);

  k_wpack<<<dim3(12, 32, NE), 256, 0, stream>>>(gate, Gpk, D_DIM, I_DIM);
  k_wpack<<<dim3(12, 32, NE), 256, 0, stream>>>(up,   Upk, D_DIM, I_DIM);
  k_xpack<<<dim3(8, 16, NE),  256, 0, stream>>>(xb, counts, slot_token, xeT);
  k_mlp1p<<<dim3(1536), 512, 131072, stream>>>(xeT, Gpk, Upk, counts, hP);
  k_wpack<<<dim3(32, 12, NE), 256, 0, stream>>>(down, Dpk, I_DIM, D_DIM);  // aliases xeT
  k_mlp2p<<<dim3(2048), 512, 131072, stream>>>(hP, Dpk, counts, slot_token, slot_w, out);
}

// Round 10
// 1248.918 us; speedup vs baseline: 1.6008x; 1.0786x over previous
//
#include <hip/hip_runtime.h>
#include <hip/hip_bf16.h>

typedef __attribute__((ext_vector_type(4))) float f32x4;
typedef __attribute__((ext_vector_type(8))) short bf16x8;
typedef __attribute__((ext_vector_type(8))) unsigned short us8;
typedef unsigned int   u32;
typedef unsigned short u16;

#define D_DIM 2048
#define I_DIM 768
#define NE    64
#define CAP   1024
#define NTOK  4096

__device__ __forceinline__ u32 cvt2(float a, float b) {
  __hip_bfloat162 hh = __float22bfloat162_rn(float2{a, b});
  union { __hip_bfloat162 h; u32 u; } c; c.h = hh; return c.u;
}
__device__ __forceinline__ u16 f2b(float f) {
  __hip_bfloat16 b = __float2bfloat16(f);
  union { __hip_bfloat16 b; u16 u; } c; c.b = b; return c.u;
}
__device__ __forceinline__ float b2f(u16 v) {
  union { u32 u; float f; } c; c.u = (u32)v << 16; return c.f;
}
// async global->LDS, 16B per lane. LDS dest = wave-uniform base + lane*16.
__device__ __forceinline__ void glp16(const void* g, void* l) {
  __builtin_amdgcn_global_load_lds(
      (const __attribute__((address_space(1))) u32*)g,
      (__attribute__((address_space(3))) u32*)l, 16, 0, 0);
}

#define VMW(n) asm volatile("s_waitcnt vmcnt(" #n ")" ::: "memory")
#define BARF   do { __builtin_amdgcn_s_barrier(); \
                    asm volatile("" ::: "memory"); } while (0)

// ---------------- x fp32 -> bf16 ----------------
__global__ __launch_bounds__(256) void k_cvt_x(const float* __restrict__ x,
                                               u16* __restrict__ xb) {
  const size_t i = ((size_t)blockIdx.x * 256 + threadIdx.x) * 8;
  float4 v0 = *(const float4*)(x + i);
  float4 v1 = *(const float4*)(x + i + 4);
  uint4 o;
  o.x = cvt2(v0.x, v0.y); o.y = cvt2(v0.z, v0.w);
  o.z = cvt2(v1.x, v1.y); o.w = cvt2(v1.z, v1.w);
  *(uint4*)(xb + i) = o;
}

// ---------------- router: fp32 logits, top-8, renorm, dispatch ----------------
__global__ __launch_bounds__(256) void k_router(
    const float* __restrict__ x, const float* __restrict__ rw,
    int* __restrict__ counts, int* __restrict__ slot_token,
    float* __restrict__ slot_w)
{
  const int lane = threadIdx.x & 63;
  const int tok  = blockIdx.x * 4 + (threadIdx.x >> 6);
  const float* xr = x + (size_t)tok * D_DIM;

  float acc = 0.f;
  for (int d0 = 0; d0 < D_DIM; d0 += 64) {
    float xv = xr[d0 + lane];
    #pragma unroll
    for (int j = 0; j < 64; ++j) {
      float xj = __shfl(xv, j, 64);
      acc = fmaf(xj, rw[(size_t)(d0 + j) * NE + lane], acc);
    }
  }

  float v = acc; int vi = lane;
  float wk[8]; int ei[8];
  float mx0 = 0.f, wsum = 0.f;
  #pragma unroll
  for (int k = 0; k < 8; ++k) {
    float mv = v; int mi = vi;
    #pragma unroll
    for (int off = 32; off >= 1; off >>= 1) {
      float ov = __shfl_xor(mv, off, 64);
      int   oi = __shfl_xor(mi, off, 64);
      if (ov > mv || (ov == mv && oi < mi)) { mv = ov; mi = oi; }
    }
    if (k == 0) mx0 = mv;
    float ew = __expf(mv - mx0);
    wk[k] = ew; ei[k] = mi; wsum += ew;
    if (lane == mi) v = -3.4e38f;
  }

  if (lane == 0) {
    float inv = 1.f / wsum;
    #pragma unroll
    for (int k = 0; k < 8; ++k) {
      int ee   = ei[k];
      int slot = atomicAdd(&counts[ee], 1);
      if (slot < CAP) {
        slot_token[ee * CAP + slot] = tok;
        slot_w[ee * CAP + slot]     = wk[k] * inv;
      }
    }
  }
}

// ---------------- inverse map: (e,slot) -> per-token index list --------------
// run AFTER mlp1p (its storage region is xeT's tail, dead by then)
__global__ __launch_bounds__(256) void k_inv(
    const int* __restrict__ counts, const int* __restrict__ slot_token,
    int* __restrict__ tok_cnt, int* __restrict__ tok_idx)
{
  const int e = blockIdx.x;
  int cnt = counts[e]; if (cnt > CAP) cnt = CAP;
  for (int s = threadIdx.x; s < cnt; s += 256) {
    const int tok = slot_token[e * CAP + s];
    const int pos = atomicAdd(&tok_cnt[tok], 1);
    if (pos < 8) tok_idx[tok * 8 + pos] = e * CAP + s;
  }
}

// ---------------- weight pack: fp32 [R][C] -> bf16 [C/64][R/8][64][8] per e ----
__global__ __launch_bounds__(256) void k_wpack(const float* __restrict__ in,
                                               u16* __restrict__ outp,
                                               int R, int C) {
  const int e  = blockIdx.z;
  const int c0 = blockIdx.x * 64;
  const int r0 = blockIdx.y * 64;
  const float* ip = in + (size_t)e * R * C;
  u16* op = outp + (size_t)e * (size_t)(C / 64) * (R / 8) * 512
                 + ((size_t)(c0 / 64) * (R / 8) + (r0 / 8)) * 512;

  __shared__ u16 T[64][76];     // T[n][k]
  const int t  = threadIdx.x;
  const int rr = t >> 4;        // 0..15 (k)
  const int cc = (t & 15) * 4;  // 0..60 (n)
  #pragma unroll
  for (int it = 0; it < 4; ++it) {
    const int r = rr + it * 16;
    float4 v = *(const float4*)(ip + (size_t)(r0 + r) * C + c0 + cc);
    T[cc + 0][r] = f2b(v.x);
    T[cc + 1][r] = f2b(v.y);
    T[cc + 2][r] = f2b(v.z);
    T[cc + 3][r] = f2b(v.w);
  }
  __syncthreads();
  const int n = t & 63;
  #pragma unroll
  for (int p = 0; p < 2; ++p) {
    const int c = (t >> 6) + p * 4;           // kcell 0..7
    const u16* s = &T[n][c * 8];
    uint4 o;
    o.x = (u32)s[0] | ((u32)s[1] << 16);
    o.y = (u32)s[2] | ((u32)s[3] << 16);
    o.z = (u32)s[4] | ((u32)s[5] << 16);
    o.w = (u32)s[6] | ((u32)s[7] << 16);
    *(uint4*)(op + ((size_t)c * 64 + n) * 8) = o;
  }
}

// ---------------- x pack: gather tokens -> xeT[e][kcell(256)][1024][8] --------
__global__ __launch_bounds__(256) void k_xpack(
    const u16* __restrict__ xb, const int* __restrict__ counts,
    const int* __restrict__ slot_token, u16* __restrict__ xeT)
{
  const int e   = blockIdx.z;
  const int s0  = blockIdx.y * 64;
  const int kc0 = blockIdx.x * 32;
  int cnt = counts[e]; if (cnt > CAP) cnt = CAP;

  __shared__ u16 T[64][264];
  const int t = threadIdx.x;
  const int r = t >> 2;
  const int q = t & 3;
  const int  tok  = slot_token[e * CAP + s0 + r];
  const bool live = (s0 + r) < cnt;
  const u16* src = xb + (size_t)tok * D_DIM + kc0 * 8;

  #pragma unroll
  for (int it = 0; it < 8; ++it) {
    const int kl = it * 32 + q * 8;
    us8 v = {0, 0, 0, 0, 0, 0, 0, 0};
    if (live) v = *(const us8*)(src + kl);
    *(us8*)&T[r][kl] = v;
  }
  __syncthreads();

  u16* dst = xeT + (size_t)e * 2097152 + (size_t)kc0 * 8192 + (size_t)s0 * 8;
  const int sl = t & 63;
  #pragma unroll
  for (int p = 0; p < 8; ++p) {
    const int c = (t >> 6) + p * 4;
    const u16* s = &T[sl][c * 8];
    uint4 o = *(const uint4*)s;
    *(uint4*)(dst + (size_t)c * 8192 + sl * 8) = o;
  }
}

// ================= big-tile GEMMs: 512 thr, ring-4 128KB LDS, depth-3 vmcnt ===

// ---- mlp1 helpers: tile 256m x 128i (gate+up), wave = 64m x 64i x {g,u} ----
__device__ __forceinline__ void m1_issue(
    const u16* xeA, const u16* gbp, const u16* ubp, u16* sm,
    int js, int sb, int wv, int lane, int m0)
{
  const int st = sb * 16384;
  if (wv < 4) {
    const u16* s = xeA + (size_t)(js * 4) * 8192 + (size_t)(m0 + wv * 64 + lane) * 8;
    u16* d = sm + st + (wv * 64) * 8;
    glp16(s,         d);
    glp16(s + 8192,  d + 2048);
    glp16(s + 16384, d + 4096);
    glp16(s + 24576, d + 6144);
  } else {
    const int w2 = wv & 1;
    const u16* base = (wv >= 6) ? ubp : gbp;
    const u16* s = base + (size_t)w2 * 131072 + (size_t)(js * 4) * 512 + lane * 8;
    u16* d = sm + st + ((wv >= 6) ? 12288 : 8192) + (w2 * 64) * 8;
    glp16(s,        d);
    glp16(s + 512,  d + 1024);
    glp16(s + 1024, d + 2048);
    glp16(s + 1536, d + 3072);
  }
}

__device__ __forceinline__ void m1_step(
    const u16* sm, int st, int gq, int li, int mrow, int icol,
    f32x4 (&ag)[4][4], f32x4 (&au)[4][4])
{
  bf16x8 a[4], g[4], u[4];
  #pragma unroll
  for (int mf = 0; mf < 4; ++mf)
    a[mf] = *(const bf16x8*)&sm[st + (gq * 256 + mrow + mf * 16 + li) * 8];
  #pragma unroll
  for (int nf = 0; nf < 4; ++nf) {
    g[nf] = *(const bf16x8*)&sm[st + 8192  + (gq * 128 + icol + nf * 16 + li) * 8];
    u[nf] = *(const bf16x8*)&sm[st + 12288 + (gq * 128 + icol + nf * 16 + li) * 8];
  }
  #pragma unroll
  for (int mf = 0; mf < 4; ++mf)
    #pragma unroll
    for (int nf = 0; nf < 4; ++nf) {
      ag[mf][nf] = __builtin_amdgcn_mfma_f32_16x16x32_bf16(a[mf], g[nf], ag[mf][nf], 0, 0, 0);
      au[mf][nf] = __builtin_amdgcn_mfma_f32_16x16x32_bf16(a[mf], u[nf], au[mf][nf], 0, 0, 0);
    }
}

// grid 1536 (4mt x 6nt x 64e), XCD-swizzled, 512 threads, 128KB dynamic LDS.
__global__ __launch_bounds__(512, 2) void k_mlp1p(
    const u16* __restrict__ xeT, const u16* __restrict__ Gpk,
    const u16* __restrict__ Upk, const int* __restrict__ counts,
    u16* __restrict__ hP)
{
  extern __shared__ u16 sm[];
  const int i   = blockIdx.x;
  const int xcd = i & 7;
  const int p   = i >> 3;          // 0..191
  const int mt  = p & 3;
  const int pe  = p >> 2;          // 0..47
  const int val = pe * 8 + xcd;    // 0..383 == e*6 + nt
  const int e   = val / 6;
  const int nt  = val % 6;

  int cnt = counts[e]; if (cnt > CAP) cnt = CAP;
  const int m0 = mt * 256;
  if (m0 >= cnt) return;

  const int t = threadIdx.x;
  const int lane = t & 63, wv = t >> 6;
  const int li = lane & 15, gq = lane >> 4;
  const int mrow = (wv >> 1) * 64, icol = (wv & 1) * 64;

  const u16* xeA = xeT + (size_t)e * 2097152;
  const u16* gbp = Gpk + (size_t)e * 1572864 + (size_t)(nt * 2) * 131072;
  const u16* ubp = Upk + (size_t)e * 1572864 + (size_t)(nt * 2) * 131072;

  f32x4 ag[4][4], au[4][4];
  #pragma unroll
  for (int mf = 0; mf < 4; ++mf)
    #pragma unroll
    for (int nf = 0; nf < 4; ++nf) {
      f32x4 z = {0.f, 0.f, 0.f, 0.f};
      ag[mf][nf] = z; au[mf][nf] = z;
    }

  m1_issue(xeA, gbp, ubp, sm, 0, 0, wv, lane, m0);
  m1_issue(xeA, gbp, ubp, sm, 1, 1, wv, lane, m0);
  m1_issue(xeA, gbp, ubp, sm, 2, 2, wv, lane, m0);

  for (int j = 0; j < 61; ++j) {           // 64 K-phases total (K=2048, BK=32)
    VMW(8); BARF;
    m1_issue(xeA, gbp, ubp, sm, j + 3, (j + 3) & 3, wv, lane, m0);
    m1_step(sm, (j & 3) * 16384, gq, li, mrow, icol, ag, au);
  }
  VMW(8); BARF; m1_step(sm, 1 * 16384, gq, li, mrow, icol, ag, au);
  VMW(4); BARF; m1_step(sm, 2 * 16384, gq, li, mrow, icol, ag, au);
  VMW(0); BARF; m1_step(sm, 3 * 16384, gq, li, mrow, icol, ag, au);

  // epilogue: h = silu(g)*u, packed hP[e][i>>3][slot][i&7]
  u16* hPe = hP + (size_t)e * 786432;
  #pragma unroll
  for (int mf = 0; mf < 4; ++mf)
    #pragma unroll
    for (int jj = 0; jj < 4; ++jj) {
      const int slot = m0 + mrow + mf * 16 + gq * 4 + jj;
      #pragma unroll
      for (int nf = 0; nf < 4; ++nf) {
        const int ii = nt * 128 + icol + nf * 16 + li;
        float gg = ag[mf][nf][jj];
        float uu = au[mf][nf][jj];
        hPe[(size_t)(ii >> 3) * 8192 + slot * 8 + (ii & 7)] =
            f2b(gg * uu / (1.f + __expf(-gg)));
      }
    }
}

// ---- mlp2 helpers: tile 256m x 256n, wave = 64m x 128n ----
__device__ __forceinline__ void m2_issue(
    const u16* hPe, const u16* dpe, u16* sm,
    int js, int sb, int wv, int lane, int m0)
{
  const int st = sb * 16384;
  if (wv < 4) {
    const u16* s = hPe + (size_t)(js * 4) * 8192 + (size_t)(m0 + wv * 64 + lane) * 8;
    u16* d = sm + st + (wv * 64) * 8;
    glp16(s,         d);
    glp16(s + 8192,  d + 2048);
    glp16(s + 16384, d + 4096);
    glp16(s + 24576, d + 6144);
  } else {
    const int w2 = wv - 4;     // 0..3 -> d-col group
    const u16* s = dpe + (size_t)w2 * 49152 + (size_t)(js * 4) * 512 + lane * 8;
    u16* d = sm + st + 8192 + (w2 * 64) * 8;
    glp16(s,        d);
    glp16(s + 512,  d + 2048);
    glp16(s + 1024, d + 4096);
    glp16(s + 1536, d + 6144);
  }
}

__device__ __forceinline__ void m2_step(
    const u16* sm, int st, int gq, int li, int mrow, int ncol,
    f32x4 (&acc)[4][8])
{
  bf16x8 a[4], b[8];
  #pragma unroll
  for (int mf = 0; mf < 4; ++mf)
    a[mf] = *(const bf16x8*)&sm[st + (gq * 256 + mrow + mf * 16 + li) * 8];
  #pragma unroll
  for (int nf = 0; nf < 8; ++nf)
    b[nf] = *(const bf16x8*)&sm[st + 8192 + (gq * 256 + ncol + nf * 16 + li) * 8];
  #pragma unroll
  for (int mf = 0; mf < 4; ++mf)
    #pragma unroll
    for (int nf = 0; nf < 8; ++nf)
      acc[mf][nf] = __builtin_amdgcn_mfma_f32_16x16x32_bf16(a[mf], b[nf], acc[mf][nf], 0, 0, 0);
}

// grid 2048 (4mt x 8nt x 64e), XCD-swizzled, 512 threads, 128KB dynamic LDS.
// epilogue: plain bf16 stores of weighted contribution into ye (no atomics).
__global__ __launch_bounds__(512, 2) void k_mlp2p(
    const u16* __restrict__ hP, const u16* __restrict__ Dpk,
    const int* __restrict__ counts, const float* __restrict__ slot_w,
    u16* __restrict__ ye)
{
  extern __shared__ u16 sm[];
  const int i   = blockIdx.x;
  const int xcd = i & 7;
  const int p   = i >> 3;          // 0..255
  const int mt  = p & 3;
  const int pe  = p >> 2;          // 0..63
  const int val = pe * 8 + xcd;    // 0..511 == e*8 + nt
  const int e   = val >> 3;
  const int nt  = val & 7;

  int cnt = counts[e]; if (cnt > CAP) cnt = CAP;
  const int m0 = mt * 256;
  if (m0 >= cnt) return;
  const int n0 = nt * 256;

  const int t = threadIdx.x;
  const int lane = t & 63, wv = t >> 6;
  const int li = lane & 15, gq = lane >> 4;
  const int mrow = (wv >> 1) * 64, ncol = (wv & 1) * 128;

  const u16* hPe = hP + (size_t)e * 786432;
  const u16* dpe = Dpk + (size_t)e * 1572864 + (size_t)(nt * 4) * 49152;

  f32x4 acc[4][8];
  #pragma unroll
  for (int mf = 0; mf < 4; ++mf)
    #pragma unroll
    for (int nf = 0; nf < 8; ++nf) { f32x4 z = {0.f,0.f,0.f,0.f}; acc[mf][nf] = z; }

  m2_issue(hPe, dpe, sm, 0, 0, wv, lane, m0);
  m2_issue(hPe, dpe, sm, 1, 1, wv, lane, m0);
  m2_issue(hPe, dpe, sm, 2, 2, wv, lane, m0);

  for (int j = 0; j < 21; ++j) {           // 24 K-phases (K=768, BK=32)
    VMW(8); BARF;
    m2_issue(hPe, dpe, sm, j + 3, (j + 3) & 3, wv, lane, m0);
    m2_step(sm, (j & 3) * 16384, gq, li, mrow, ncol, acc);
  }
  VMW(8); BARF; m2_step(sm, 1 * 16384, gq, li, mrow, ncol, acc);
  VMW(4); BARF; m2_step(sm, 2 * 16384, gq, li, mrow, ncol, acc);
  VMW(0); BARF; m2_step(sm, 3 * 16384, gq, li, mrow, ncol, acc);

  #pragma unroll
  for (int mf = 0; mf < 4; ++mf)
    #pragma unroll
    for (int jj = 0; jj < 4; ++jj) {
      const int slot = m0 + mrow + mf * 16 + gq * 4 + jj;
      if (slot < cnt) {
        const float wgt = slot_w[e * CAP + slot];
        u16* yr = ye + (size_t)(e * CAP + slot) * D_DIM + n0 + ncol + li;
        #pragma unroll
        for (int nf = 0; nf < 8; ++nf)
          yr[nf * 16] = f2b(wgt * acc[mf][nf][jj]);
      }
    }
}

// ---------------- combine: out[tok] = sum_k ye[tok_idx[tok][k]] --------------
__global__ __launch_bounds__(256) void k_combine(
    const u16* __restrict__ ye, const int* __restrict__ tok_idx,
    const int* __restrict__ tok_cnt, float* __restrict__ out)
{
  const int tok = blockIdx.x;
  const int c0  = threadIdx.x * 8;
  int cnt8 = tok_cnt[tok]; if (cnt8 > 8) cnt8 = 8;

  float s[8] = {0.f, 0.f, 0.f, 0.f, 0.f, 0.f, 0.f, 0.f};
  #pragma unroll
  for (int k = 0; k < 8; ++k) {
    if (k < cnt8) {
      const int idx = tok_idx[tok * 8 + k];
      const us8 v = *(const us8*)(ye + (size_t)idx * D_DIM + c0);
      #pragma unroll
      for (int j = 0; j < 8; ++j) s[j] += b2f(v[j]);
    }
  }
  float4 o0 = {s[0], s[1], s[2], s[3]};
  float4 o1 = {s[4], s[5], s[6], s[7]};
  float* op = out + (size_t)tok * D_DIM + c0;
  *(float4*)op       = o0;
  *(float4*)(op + 4) = o1;
}

extern "C" void kernel_launch(void* const* d_in, const int* in_sizes, int n_in,
                              void* d_out, int out_size, void* d_ws, size_t ws_size,
                              hipStream_t stream) {
  const float* x    = (const float*)d_in[0];
  const float* rw   = (const float*)d_in[1];
  const float* gate = (const float*)d_in[2];
  const float* up   = (const float*)d_in[3];
  const float* down = (const float*)d_in[4];
  float* out = (float*)d_out;

  char* ws = (char*)d_ws;
  int*   counts     = (int*)ws;
  int*   slot_token = (int*)(ws + 1024);
  float* slot_w     = (float*)(ws + 263168);
  u16*   xb         = (u16*)(ws + 525312);
  u16*   hP         = (u16*)(ws + 17302528);          // 100.66 MB
  u16*   Gpk        = (u16*)(ws + 117965824);         // 201.3 MB
  u16*   Upk        = (u16*)(ws + 319292416);         // 201.3 MB
  u16*   xeT        = (u16*)(ws + 520619008);         // 268.4 MB
  u16*   Dpk        = xeT;                            // aliased: written after mlp1
  u16*   ye         = Gpk;                            // aliased: Gpk+Upk dead after mlp1 (268.4 MB)
  int*   tok_cnt    = (int*)(ws + 721945600);         // in xeT tail, dead after mlp1 (16 KB)
  int*   tok_idx    = (int*)(ws + 721945600 + 16384); // 128 KB

  // allow 128 KB dynamic LDS (host-side attr set; not a stream op, graph-safe)
  hipFuncSetAttribute((const void*)k_mlp1p,
                      hipFuncAttributeMaxDynamicSharedMemorySize, 131072);
  hipFuncSetAttribute((const void*)k_mlp2p,
                      hipFuncAttributeMaxDynamicSharedMemorySize, 131072);

  hipMemsetAsync(counts, 0, NE * sizeof(int), stream);
  hipMemsetAsync(slot_token, 0, (size_t)NE * CAP * sizeof(int), stream);

  k_cvt_x <<<dim3((NTOK * D_DIM) / (256 * 8)), 256, 0, stream>>>(x, xb);
  k_router<<<dim3(NTOK / 4),                   256, 0, stream>>>(x, rw, counts, slot_token, slot_w);

  k_wpack<<<dim3(12, 32, NE), 256, 0, stream>>>(gate, Gpk, D_DIM, I_DIM);
  k_wpack<<<dim3(12, 32, NE), 256, 0, stream>>>(up,   Upk, D_DIM, I_DIM);
  k_xpack<<<dim3(8, 16, NE),  256, 0, stream>>>(xb, counts, slot_token, xeT);
  k_mlp1p<<<dim3(1536), 512, 131072, stream>>>(xeT, Gpk, Upk, counts, hP);

  // xeT (and its tail) dead; Gpk/Upk dead -> reuse for tok maps, Dpk, ye
  hipMemsetAsync(tok_cnt, 0, NTOK * sizeof(int), stream);
  k_inv  <<<dim3(NE), 256, 0, stream>>>(counts, slot_token, tok_cnt, tok_idx);
  k_wpack<<<dim3(32, 12, NE), 256, 0, stream>>>(down, Dpk, I_DIM, D_DIM);

  k_mlp2p  <<<dim3(2048), 512, 131072, stream>>>(hP, Dpk, counts, slot_w, ye);
  k_combine<<<dim3(NTOK), 256, 0, stream>>>(ye, tok_idx, tok_cnt, out);
}